// Round 3
// baseline (1230.337 us; speedup 1.0000x reference)
//
#include <hip/hip_runtime.h>

#define SEQ 1024
#define CDIM 256

// ---------------- workspace layout (float offsets) ----------------
static const size_t OFF_H1  = 0;                               // 4096*256
static const size_t OFF_QKV = (size_t)4096*256;                // 4096*768
static const size_t OFF_O   = OFF_QKV + (size_t)4096*768;      // 4096*256
static const size_t OFF_XR  = OFF_O   + (size_t)4096*256;      // 4096*256
static const size_t OFF_Y   = OFF_XR  + (size_t)4096*256;      // 4*2048*1024
static const size_t OFF_PA  = OFF_Y   + (size_t)4*2048*1024;   // 64*1024
static const size_t OFF_PB  = OFF_PA  + 65536;                 // 64*1024
static const size_t OFF_PM  = OFF_PB  + 65536;                 // 576*1024
static const size_t OFF_Z   = OFF_PM  + (size_t)576*1024;      // 4*1024*1024
// total = 19,595,264 floats = 78.4 MB

// ---------------- LayerNorm over C=256, one block per row ----------------
__global__ __launch_bounds__(256) void k_ln1(const float* __restrict__ x,
                                             const float* __restrict__ g,
                                             const float* __restrict__ b,
                                             float* __restrict__ h1) {
  int row = blockIdx.x, t = threadIdx.x;
  __shared__ float red[256];
  float v = x[(size_t)row*CDIM + t];
  red[t] = v; __syncthreads();
  for (int o = 128; o > 0; o >>= 1) { if (t < o) red[t] += red[t+o]; __syncthreads(); }
  float mean = red[0] * (1.f/CDIM);
  __syncthreads();
  float d = v - mean;
  red[t] = d*d; __syncthreads();
  for (int o = 128; o > 0; o >>= 1) { if (t < o) red[t] += red[t+o]; __syncthreads(); }
  float var = red[0] * (1.f/CDIM);
  h1[(size_t)row*CDIM + t] = d * rsqrtf(var + 1e-5f) * g[t] + b[t];
}

// ---------------- GEMM: C[m][n] = sum_k A[m][k]*Bt[n][k] (+bias[n]) (+resid[m][n]) ----
// A: M x K row-major (lda), Bt: N x K row-major (ldb), C: M x N (ldc)
__global__ __launch_bounds__(256) void k_gemm_abt(
    const float* __restrict__ A, const float* __restrict__ Bt, float* __restrict__ C,
    const float* __restrict__ bias, const float* __restrict__ resid,
    int K, int lda, int ldb, int ldc,
    long strideA, long strideB, long strideC) {
  __shared__ float As[16][68];
  __shared__ float Bs[16][68];
  const float* Ap = A + (size_t)blockIdx.z * strideA;
  const float* Bp = Bt + (size_t)blockIdx.z * strideB;
  float* Cp = C + (size_t)blockIdx.z * strideC;
  const float* Rp = resid ? (resid + (size_t)blockIdx.z * strideC) : nullptr;
  int m0 = blockIdx.y * 64, n0 = blockIdx.x * 64;
  int t = threadIdx.x;
  int lr = t >> 2, lk = (t & 3) * 4;   // loader: 64 rows x 16 k
  int ty = t >> 4, tx = t & 15;
  float acc[4][4] = {};
  for (int k0 = 0; k0 < K; k0 += 16) {
    float4 av = *(const float4*)&Ap[(size_t)(m0 + lr)*lda + k0 + lk];
    float4 bv = *(const float4*)&Bp[(size_t)(n0 + lr)*ldb + k0 + lk];
    As[lk+0][lr] = av.x; As[lk+1][lr] = av.y; As[lk+2][lr] = av.z; As[lk+3][lr] = av.w;
    Bs[lk+0][lr] = bv.x; Bs[lk+1][lr] = bv.y; Bs[lk+2][lr] = bv.z; Bs[lk+3][lr] = bv.w;
    __syncthreads();
#pragma unroll
    for (int kk = 0; kk < 16; ++kk) {
      float a[4], bb[4];
#pragma unroll
      for (int i = 0; i < 4; ++i) a[i] = As[kk][ty*4+i];
#pragma unroll
      for (int j = 0; j < 4; ++j) bb[j] = Bs[kk][tx*4+j];
#pragma unroll
      for (int i = 0; i < 4; ++i)
#pragma unroll
        for (int j = 0; j < 4; ++j) acc[i][j] += a[i]*bb[j];
    }
    __syncthreads();
  }
#pragma unroll
  for (int i = 0; i < 4; ++i) {
    int m = m0 + ty*4 + i;
    float4 ov;
    float* o = &ov.x;
#pragma unroll
    for (int j = 0; j < 4; ++j) {
      float vv = acc[i][j];
      int n = n0 + tx*4 + j;
      if (bias) vv += bias[n];
      if (Rp)   vv += Rp[(size_t)m*ldc + n];
      o[j] = vv;
    }
    *(float4*)&Cp[(size_t)m*ldc + n0 + tx*4] = ov;
  }
}

// ---------------- attention: dual sparse/dense blend ----------------
// qkv layout: [b][n][tq*256 + h*32 + d], tq in {0:q,1:k,2:v}
__global__ __launch_bounds__(256) void k_attn(const float* __restrict__ qkv,
                                              const float* __restrict__ alpha,
                                              const float* __restrict__ beta,
                                              float* __restrict__ o_out) {
  __shared__ float S[8][1028];     // padded stride: banks spread over r
  __shared__ float ks[128][36];    // K or V chunk
  __shared__ float mmax[8], dsum[8], ssum[8];
  int bh = blockIdx.x >> 7, rblk = blockIdx.x & 127;
  int b = bh >> 3, h = bh & 7;
  int t = threadIdx.x;
  int r = t >> 5, dl = t & 31;
  const float scale = 0.17677669529663687f;  // 32^-0.5
  // q row -> registers
  float qreg[32];
  {
    const float* qp = qkv + ((size_t)(b*SEQ + rblk*8 + r))*768 + h*32;
#pragma unroll
    for (int d4 = 0; d4 < 8; ++d4) {
      float4 v = *(const float4*)&qp[d4*4];
      qreg[d4*4+0]=v.x; qreg[d4*4+1]=v.y; qreg[d4*4+2]=v.z; qreg[d4*4+3]=v.w;
    }
  }
  // phase 1: S = q K^T * scale
  for (int kc = 0; kc < SEQ; kc += 128) {
    __syncthreads();
#pragma unroll
    for (int u = 0; u < 4; ++u) {
      int idx = t + u*256;           // float4 units: 1024 total
      int key = idx >> 3, dq = idx & 7;
      float4 v = *(const float4*)&qkv[((size_t)(b*SEQ + kc + key))*768 + 256 + h*32 + dq*4];
      ks[key][dq*4+0]=v.x; ks[key][dq*4+1]=v.y; ks[key][dq*4+2]=v.z; ks[key][dq*4+3]=v.w;
    }
    __syncthreads();
#pragma unroll
    for (int c = 0; c < 4; ++c) {
      int key = dl + c*32;
      const float4* krow = (const float4*)&ks[key][0];
      float acc = 0.f;
#pragma unroll
      for (int d4 = 0; d4 < 8; ++d4) {
        float4 kv = krow[d4];
        acc += qreg[d4*4+0]*kv.x + qreg[d4*4+1]*kv.y + qreg[d4*4+2]*kv.z + qreg[d4*4+3]*kv.w;
      }
      S[r][kc + key] = acc * scale;
    }
  }
  __syncthreads();
  // phase 2: per-row stats (one wave handles 2 rows)
  {
    int wv = t >> 6, lane = t & 63;
    for (int rr = 0; rr < 2; ++rr) {
      int rw = wv*2 + rr;
      float m = -1e30f;
      for (int k = lane; k < SEQ; k += 64) m = fmaxf(m, S[rw][k]);
#pragma unroll
      for (int o = 32; o > 0; o >>= 1) m = fmaxf(m, __shfl_xor(m, o));
      float se = 0.f, sq = 0.f;
      for (int k = lane; k < SEQ; k += 64) {
        float s = S[rw][k];
        float rl = fmaxf(s, 0.f);
        sq += rl*rl;
        se += __expf(s - m);
      }
#pragma unroll
      for (int o = 32; o > 0; o >>= 1) { se += __shfl_xor(se, o); sq += __shfl_xor(sq, o); }
      if (lane == 0) { mmax[rw] = m; dsum[rw] = se; ssum[rw] = sq; }
    }
  }
  __syncthreads();
  // phase 2.5: S <- blended attention weights
  float a_s = 1.f/(1.f+__expf(-alpha[0]));
  float b_s = 1.f/(1.f+__expf(-beta[0]));
  float wsn = a_s + b_s + 1e-8f;
  float afac = a_s/wsn, bfac = b_s/wsn;
  for (int idx = t; idx < 8*SEQ; idx += 256) {
    int rr = idx >> 10, k = idx & 1023;
    float s = S[rr][k];
    float rl = fmaxf(s, 0.f);
    S[rr][k] = afac * rl*rl / (ssum[rr] + 1e-8f) + bfac * __expf(s - mmax[rr]) / dsum[rr];
  }
  // phase 3: o = af @ V (V staged in LDS chunks)
  float acc = 0.f;
  for (int kc = 0; kc < SEQ; kc += 128) {
    __syncthreads();
#pragma unroll
    for (int u = 0; u < 4; ++u) {
      int idx = t + u*256;
      int key = idx >> 3, dq = idx & 7;
      float4 v = *(const float4*)&qkv[((size_t)(b*SEQ + kc + key))*768 + 512 + h*32 + dq*4];
      ks[key][dq*4+0]=v.x; ks[key][dq*4+1]=v.y; ks[key][dq*4+2]=v.z; ks[key][dq*4+3]=v.w;
    }
    __syncthreads();
#pragma unroll 8
    for (int kk = 0; kk < 128; ++kk) acc += S[r][kc + kk] * ks[kk][dl];
  }
  o_out[((size_t)(b*SEQ + rblk*8 + r))*CDIM + h*32 + dl] = acc;
}

// ---------------- small 3x3 conv (SAME), grid (Cout, 4), one px/thread ----------------
__global__ __launch_bounds__(256) void k_conv3(const float* __restrict__ in,
                                               const float* __restrict__ w,
                                               float* __restrict__ out, int Cin) {
  int oc = blockIdx.x;
  int p = blockIdx.y * 256 + threadIdx.x;
  int y = p >> 5, x = p & 31;
  float acc = 0.f;
  for (int c = 0; c < Cin; ++c) {
    const float* ip = in + c*1024;
    const float* wp = w + ((size_t)oc*Cin + c)*9;
#pragma unroll
    for (int i = 0; i < 3; ++i) {
      int yy = y + i - 1;
      if (yy < 0 || yy > 31) continue;
#pragma unroll
      for (int j = 0; j < 3; ++j) {
        int xx = x + j - 1;
        if (xx < 0 || xx > 31) continue;
        acc += ip[yy*32 + xx] * wp[i*3 + j];
      }
    }
  }
  out[oc*1024 + p] = acc;
}

// ---------------- LayerNorm over (C,H,W)=65536 + ReLU, single block ----------------
__global__ __launch_bounds__(1024) void k_lnchw(const float* __restrict__ in,
                                                const float* __restrict__ g,
                                                const float* __restrict__ b,
                                                float* __restrict__ out) {
  __shared__ float red[1024];
  __shared__ float red2[1024];
  int t = threadIdx.x;
  float s = 0.f, sq = 0.f;
  for (int i = t; i < 65536; i += 1024) { float v = in[i]; s += v; sq += v*v; }
  red[t] = s; red2[t] = sq; __syncthreads();
  for (int o = 512; o > 0; o >>= 1) {
    if (t < o) { red[t] += red[t+o]; red2[t] += red2[t+o]; }
    __syncthreads();
  }
  float mean = red[0] * (1.f/65536.f);
  float var  = red2[0] * (1.f/65536.f) - mean*mean;
  float inv = rsqrtf(var + 1e-5f);
  for (int i = t; i < 65536; i += 1024) {
    float v = (in[i] - mean) * inv * g[i] + b[i];
    out[i] = fmaxf(v, 0.f);
  }
}

// ---------------- im2col of p (64,32,32) -> pm[576][1024] ----------------
__global__ __launch_bounds__(256) void k_im2col(const float* __restrict__ p,
                                                float* __restrict__ pm) {
  int idx = blockIdx.x * 256 + threadIdx.x;   // 589824 total
  int n = idx & 1023, rowi = idx >> 10;
  int c = rowi / 9, tap = rowi % 9;
  int y = n >> 5, x = n & 31;
  int yy = y + tap/3 - 1, xx = x + tap%3 - 1;
  float v = (yy >= 0 && yy < 32 && xx >= 0 && xx < 32) ? p[c*1024 + yy*32 + xx] : 0.f;
  pm[idx] = v;
}

__device__ __forceinline__ float gelu_exact(float x) {
  return 0.5f * x * (1.f + erff(x * 0.70710678118654752f));
}

// ------- fused cf conv (GEMM 18432x1024x576) + TVConv + GELU gate -> z -------
// block: rows = channels {c0..c0+3} and {c0+1024..c0+1027} x 9 taps (72 rows), cols = 128 hw
__global__ __launch_bounds__(256) void k_cf_tv(const float* __restrict__ cfw,
                                               const float* __restrict__ pm,
                                               const float* __restrict__ y,
                                               float* __restrict__ z) {
  __shared__ float As[36][80];
  __shared__ float Bs[36][128];
  __shared__ float zb1[4][128];
  __shared__ float zb2[4][128];
  int c0 = blockIdx.y * 4;
  int n0 = blockIdx.x * 128;
  int t = threadIdx.x;
  int ty = t >> 5, tx = t & 31;
  float acc[9][4] = {};
  for (int k0 = 0; k0 < 576; k0 += 36) {
    __syncthreads();
    for (int idx = t; idx < 2592; idx += 256) {
      int rr = idx / 36, kk = idx % 36;
      int grow = (rr < 36) ? (c0*9 + rr) : ((c0 + 1024)*9 + (rr - 36));
      As[kk][rr] = cfw[(size_t)grow*576 + k0 + kk];
    }
    for (int idx = t; idx < 4608; idx += 256) {
      int kk = idx >> 7, col = idx & 127;
      Bs[kk][col] = pm[(size_t)(k0 + kk)*1024 + n0 + col];
    }
    __syncthreads();
#pragma unroll 6
    for (int kk = 0; kk < 36; ++kk) {
      float4 b4 = *(const float4*)&Bs[kk][tx*4];
#pragma unroll
      for (int i = 0; i < 9; ++i) {
        float a = As[kk][ty*9 + i];
        acc[i][0] += a * b4.x; acc[i][1] += a * b4.y;
        acc[i][2] += a * b4.z; acc[i][3] += a * b4.w;
      }
    }
  }
  // epilogue: TVConv over 9 taps, then gate pairs (c, c+1024)
  int ch = (ty < 4) ? (c0 + ty) : (c0 + 1024 + (ty - 4));
  for (int bb = 0; bb < 4; ++bb) {
    const float* yp = y + ((size_t)bb*2048 + ch)*1024;
    float outv[4];
#pragma unroll
    for (int j = 0; j < 4; ++j) {
      int n = n0 + tx*4 + j;
      int yy = n >> 5, xx = n & 31;
      float o = 0.f;
#pragma unroll
      for (int i = 0; i < 9; ++i) {
        int y2 = yy + (i/3) - 1, x2 = xx + (i%3) - 1;
        if (y2 >= 0 && y2 < 32 && x2 >= 0 && x2 < 32)
          o += acc[i][j] * yp[y2*32 + x2];
      }
      outv[j] = o;
    }
    __syncthreads();
    if (ty < 4) {
#pragma unroll
      for (int j = 0; j < 4; ++j) zb1[ty][tx*4+j] = gelu_exact(outv[j]);
    } else {
#pragma unroll
      for (int j = 0; j < 4; ++j) zb2[ty-4][tx*4+j] = outv[j];
    }
    __syncthreads();
    if (ty < 4) {
      float4 zz;
      zz.x = zb1[ty][tx*4+0] * zb2[ty][tx*4+0];
      zz.y = zb1[ty][tx*4+1] * zb2[ty][tx*4+1];
      zz.z = zb1[ty][tx*4+2] * zb2[ty][tx*4+2];
      zz.w = zb1[ty][tx*4+3] * zb2[ty][tx*4+3];
      *(float4*)&z[((size_t)bb*1024 + (c0 + ty))*1024 + n0 + tx*4] = zz;
    }
  }
}

// -------- pout GEMM: OUT[b][m][o] = xr[b][m][o] + sum_c z[b][c][m]*pw[o][c] --------
__global__ __launch_bounds__(256) void k_gemm_pout(const float* __restrict__ zbuf,
                                                   const float* __restrict__ pw,
                                                   const float* __restrict__ xr,
                                                   float* __restrict__ outp) {
  __shared__ float As[16][68];   // As[kk][m]
  __shared__ float Bs[16][68];   // Bs[kk][o]
  int b = blockIdx.z;
  int m0 = blockIdx.y * 64, n0 = blockIdx.x * 64;
  int t = threadIdx.x;
  const float* zp = zbuf + (size_t)b*1024*1024;
  int ty = t >> 4, tx = t & 15;
  int ak = t >> 4, am = (t & 15) * 4;   // A loader: 16 k x 64 m
  int br = t >> 2, bk = (t & 3) * 4;    // B loader: 64 o x 16 k
  float acc[4][4] = {};
  for (int k0 = 0; k0 < 1024; k0 += 16) {
    float4 av = *(const float4*)&zp[(size_t)(k0 + ak)*1024 + m0 + am];
    float4 bv = *(const float4*)&pw[(size_t)(n0 + br)*1024 + k0 + bk];
    As[ak][am+0]=av.x; As[ak][am+1]=av.y; As[ak][am+2]=av.z; As[ak][am+3]=av.w;
    Bs[bk+0][br]=bv.x; Bs[bk+1][br]=bv.y; Bs[bk+2][br]=bv.z; Bs[bk+3][br]=bv.w;
    __syncthreads();
#pragma unroll
    for (int kk = 0; kk < 16; ++kk) {
      float a[4], bb2[4];
#pragma unroll
      for (int i = 0; i < 4; ++i) a[i] = As[kk][ty*4+i];
#pragma unroll
      for (int j = 0; j < 4; ++j) bb2[j] = Bs[kk][tx*4+j];
#pragma unroll
      for (int i = 0; i < 4; ++i)
#pragma unroll
        for (int j = 0; j < 4; ++j) acc[i][j] += a[i]*bb2[j];
    }
    __syncthreads();
  }
#pragma unroll
  for (int i = 0; i < 4; ++i) {
    int m = m0 + ty*4 + i;
    size_t base = ((size_t)b*1024 + m)*256 + n0 + tx*4;
    float4 rv = *(const float4*)&xr[base];
    float4 ov;
    ov.x = acc[i][0] + rv.x; ov.y = acc[i][1] + rv.y;
    ov.z = acc[i][2] + rv.z; ov.w = acc[i][3] + rv.w;
    *(float4*)&outp[base] = ov;
  }
}

extern "C" void kernel_launch(void* const* d_in, const int* in_sizes, int n_in,
                              void* d_out, int out_size, void* d_ws, size_t ws_size,
                              hipStream_t stream) {
  (void)in_sizes; (void)n_in; (void)out_size; (void)ws_size;
  const float* x      = (const float*)d_in[0];
  const float* n1g    = (const float*)d_in[1];
  const float* n1b    = (const float*)d_in[2];
  const float* qkv_w  = (const float*)d_in[3];
  const float* alpha  = (const float*)d_in[4];
  const float* beta   = (const float*)d_in[5];
  const float* proj_w = (const float*)d_in[6];
  const float* proj_b = (const float*)d_in[7];
  const float* pin_w  = (const float*)d_in[8];
  const float* posi   = (const float*)d_in[9];
  const float* c0w    = (const float*)d_in[10];
  const float* l0g    = (const float*)d_in[11];
  const float* l0b    = (const float*)d_in[12];
  const float* c1w    = (const float*)d_in[13];
  const float* l1g    = (const float*)d_in[14];
  const float* l1b    = (const float*)d_in[15];
  const float* c2w    = (const float*)d_in[16];
  const float* l2g    = (const float*)d_in[17];
  const float* l2b    = (const float*)d_in[18];
  const float* cfw    = (const float*)d_in[19];
  const float* poutw  = (const float*)d_in[20];

  float* ws   = (float*)d_ws;
  float* h1   = ws + OFF_H1;
  float* qkvb = ws + OFF_QKV;
  float* ob   = ws + OFF_O;
  float* xr   = ws + OFF_XR;
  float* yb   = ws + OFF_Y;
  float* pA   = ws + OFF_PA;
  float* pB   = ws + OFF_PB;
  float* pm   = ws + OFF_PM;
  float* zb   = ws + OFF_Z;
  float* outp = (float*)d_out;

  // ASSA branch
  k_ln1<<<4096, 256, 0, stream>>>(x, n1g, n1b, h1);
  k_gemm_abt<<<dim3(12, 64, 1), 256, 0, stream>>>(h1, qkv_w, qkvb, nullptr, nullptr,
      256, 256, 256, 768, 0, 0, 0);
  k_attn<<<4096, 256, 0, stream>>>(qkvb, alpha, beta, ob);
  k_gemm_abt<<<dim3(4, 64, 1), 256, 0, stream>>>(ob, proj_w, xr, proj_b, x,
      256, 256, 256, 256, 0, 0, 0);
  // FRFN: project_in (per-batch), y[b][o][n]
  k_gemm_abt<<<dim3(16, 32, 4), 256, 0, stream>>>(pin_w, xr, yb, nullptr, nullptr,
      256, 256, 256, 1024, 0, 1024L*256, 2048L*1024);
  // posi-map conv/LN chain
  k_conv3<<<dim3(64, 4), 256, 0, stream>>>(posi, c0w, pA, 4);
  k_lnchw<<<1, 1024, 0, stream>>>(pA, l0g, l0b, pB);
  k_conv3<<<dim3(64, 4), 256, 0, stream>>>(pB, c1w, pA, 64);
  k_lnchw<<<1, 1024, 0, stream>>>(pA, l1g, l1b, pB);
  k_conv3<<<dim3(64, 4), 256, 0, stream>>>(pB, c2w, pA, 64);
  k_lnchw<<<1, 1024, 0, stream>>>(pA, l2g, l2b, pB);
  k_im2col<<<2304, 256, 0, stream>>>(pB, pm);
  // cf conv GEMM + TVConv + gate
  k_cf_tv<<<dim3(8, 256, 1), 256, 0, stream>>>(cfw, pm, yb, zb);
  // project_out + residual -> d_out
  k_gemm_pout<<<dim3(4, 16, 4), 256, 0, stream>>>(zb, poutw, xr, outp);
}

// Round 5
// 878.189 us; speedup vs baseline: 1.4010x; 1.4010x over previous
//
#include <hip/hip_runtime.h>

#define SEQ 1024
#define CDIM 256

typedef short bf16x8 __attribute__((ext_vector_type(8)));
typedef float f32x4 __attribute__((ext_vector_type(4)));

// ---------------- workspace layout (float offsets, with lifetime aliasing) ----
// [0 .. 1,048,576)        h1 (phase1)   | pA/pB (conv chain) | z (cf_tv..pout)
// [1,048,576 .. 4,194,304) qkv (phase1) | z tail
// [4,194,304 .. 5,242,880) o (attn)     | pmT (bf16, im2colT..cf_tv)
// [5,242,880 .. 6,291,456) xr (live to end)
// [6,291,456 .. 14,680,064) y
static const size_t OFF_H1  = 0;
static const size_t OFF_QKV = 1048576;
static const size_t OFF_Z   = 0;          // aliases h1+qkv (dead after attn)
static const size_t OFF_O   = 4194304;
static const size_t OFF_PMT = 4194304;    // aliases o (dead after proj)
static const size_t OFF_XR  = 5242880;
static const size_t OFF_Y   = 6291456;
static const size_t OFF_PA  = 0;          // aliases h1 (dead after qkv gemm)
static const size_t OFF_PB  = 65536;
// total = 14,680,064 floats = 58.7 MB

__device__ __forceinline__ unsigned bf16rn(float x) {
  unsigned u = __float_as_uint(x);
  return (u + 0x7fffu + ((u >> 16) & 1u)) >> 16;
}

// ---------------- LayerNorm over C=256, one block per row ----------------
__global__ __launch_bounds__(256) void k_ln1(const float* __restrict__ x,
                                             const float* __restrict__ g,
                                             const float* __restrict__ b,
                                             float* __restrict__ h1) {
  int row = blockIdx.x, t = threadIdx.x;
  __shared__ float red[256];
  float v = x[(size_t)row*CDIM + t];
  red[t] = v; __syncthreads();
  for (int o = 128; o > 0; o >>= 1) { if (t < o) red[t] += red[t+o]; __syncthreads(); }
  float mean = red[0] * (1.f/CDIM);
  __syncthreads();
  float d = v - mean;
  red[t] = d*d; __syncthreads();
  for (int o = 128; o > 0; o >>= 1) { if (t < o) red[t] += red[t+o]; __syncthreads(); }
  float var = red[0] * (1.f/CDIM);
  h1[(size_t)row*CDIM + t] = d * rsqrtf(var + 1e-5f) * g[t] + b[t];
}

// ---------------- GEMM: C[m][n] = sum_k A[m][k]*Bt[n][k] (+bias[n]) (+resid[m][n]) ----
__global__ __launch_bounds__(256) void k_gemm_abt(
    const float* __restrict__ A, const float* __restrict__ Bt, float* __restrict__ C,
    const float* __restrict__ bias, const float* __restrict__ resid,
    int K, int lda, int ldb, int ldc,
    long strideA, long strideB, long strideC) {
  __shared__ float As[16][68];
  __shared__ float Bs[16][68];
  const float* Ap = A + (size_t)blockIdx.z * strideA;
  const float* Bp = Bt + (size_t)blockIdx.z * strideB;
  float* Cp = C + (size_t)blockIdx.z * strideC;
  const float* Rp = resid ? (resid + (size_t)blockIdx.z * strideC) : nullptr;
  int m0 = blockIdx.y * 64, n0 = blockIdx.x * 64;
  int t = threadIdx.x;
  int lr = t >> 2, lk = (t & 3) * 4;
  int ty = t >> 4, tx = t & 15;
  float acc[4][4] = {};
  for (int k0 = 0; k0 < K; k0 += 16) {
    float4 av = *(const float4*)&Ap[(size_t)(m0 + lr)*lda + k0 + lk];
    float4 bv = *(const float4*)&Bp[(size_t)(n0 + lr)*ldb + k0 + lk];
    As[lk+0][lr] = av.x; As[lk+1][lr] = av.y; As[lk+2][lr] = av.z; As[lk+3][lr] = av.w;
    Bs[lk+0][lr] = bv.x; Bs[lk+1][lr] = bv.y; Bs[lk+2][lr] = bv.z; Bs[lk+3][lr] = bv.w;
    __syncthreads();
#pragma unroll
    for (int kk = 0; kk < 16; ++kk) {
      float a[4], bb[4];
#pragma unroll
      for (int i = 0; i < 4; ++i) a[i] = As[kk][ty*4+i];
#pragma unroll
      for (int j = 0; j < 4; ++j) bb[j] = Bs[kk][tx*4+j];
#pragma unroll
      for (int i = 0; i < 4; ++i)
#pragma unroll
        for (int j = 0; j < 4; ++j) acc[i][j] += a[i]*bb[j];
    }
    __syncthreads();
  }
#pragma unroll
  for (int i = 0; i < 4; ++i) {
    int m = m0 + ty*4 + i;
    float4 ov;
    float* o = &ov.x;
#pragma unroll
    for (int j = 0; j < 4; ++j) {
      float vv = acc[i][j];
      int n = n0 + tx*4 + j;
      if (bias) vv += bias[n];
      if (Rp)   vv += Rp[(size_t)m*ldc + n];
      o[j] = vv;
    }
    *(float4*)&Cp[(size_t)m*ldc + n0 + tx*4] = ov;
  }
}

// ---------------- attention: dual sparse/dense blend ----------------
__global__ __launch_bounds__(256) void k_attn(const float* __restrict__ qkv,
                                              const float* __restrict__ alpha,
                                              const float* __restrict__ beta,
                                              float* __restrict__ o_out) {
  __shared__ float S[8][1028];
  __shared__ float ks[128][36];
  __shared__ float mmax[8], dsum[8], ssum[8];
  int bh = blockIdx.x >> 7, rblk = blockIdx.x & 127;
  int b = bh >> 3, h = bh & 7;
  int t = threadIdx.x;
  int r = t >> 5, dl = t & 31;
  const float scale = 0.17677669529663687f;
  float qreg[32];
  {
    const float* qp = qkv + ((size_t)(b*SEQ + rblk*8 + r))*768 + h*32;
#pragma unroll
    for (int d4 = 0; d4 < 8; ++d4) {
      float4 v = *(const float4*)&qp[d4*4];
      qreg[d4*4+0]=v.x; qreg[d4*4+1]=v.y; qreg[d4*4+2]=v.z; qreg[d4*4+3]=v.w;
    }
  }
  for (int kc = 0; kc < SEQ; kc += 128) {
    __syncthreads();
#pragma unroll
    for (int u = 0; u < 4; ++u) {
      int idx = t + u*256;
      int key = idx >> 3, dq = idx & 7;
      float4 v = *(const float4*)&qkv[((size_t)(b*SEQ + kc + key))*768 + 256 + h*32 + dq*4];
      ks[key][dq*4+0]=v.x; ks[key][dq*4+1]=v.y; ks[key][dq*4+2]=v.z; ks[key][dq*4+3]=v.w;
    }
    __syncthreads();
#pragma unroll
    for (int c = 0; c < 4; ++c) {
      int key = dl + c*32;
      const float4* krow = (const float4*)&ks[key][0];
      float acc = 0.f;
#pragma unroll
      for (int d4 = 0; d4 < 8; ++d4) {
        float4 kv = krow[d4];
        acc += qreg[d4*4+0]*kv.x + qreg[d4*4+1]*kv.y + qreg[d4*4+2]*kv.z + qreg[d4*4+3]*kv.w;
      }
      S[r][kc + key] = acc * scale;
    }
  }
  __syncthreads();
  {
    int wv = t >> 6, lane = t & 63;
    for (int rr = 0; rr < 2; ++rr) {
      int rw = wv*2 + rr;
      float m = -1e30f;
      for (int k = lane; k < SEQ; k += 64) m = fmaxf(m, S[rw][k]);
#pragma unroll
      for (int o = 32; o > 0; o >>= 1) m = fmaxf(m, __shfl_xor(m, o));
      float se = 0.f, sq = 0.f;
      for (int k = lane; k < SEQ; k += 64) {
        float s = S[rw][k];
        float rl = fmaxf(s, 0.f);
        sq += rl*rl;
        se += __expf(s - m);
      }
#pragma unroll
      for (int o = 32; o > 0; o >>= 1) { se += __shfl_xor(se, o); sq += __shfl_xor(sq, o); }
      if (lane == 0) { mmax[rw] = m; dsum[rw] = se; ssum[rw] = sq; }
    }
  }
  __syncthreads();
  float a_s = 1.f/(1.f+__expf(-alpha[0]));
  float b_s = 1.f/(1.f+__expf(-beta[0]));
  float wsn = a_s + b_s + 1e-8f;
  float afac = a_s/wsn, bfac = b_s/wsn;
  for (int idx = t; idx < 8*SEQ; idx += 256) {
    int rr = idx >> 10, k = idx & 1023;
    float s = S[rr][k];
    float rl = fmaxf(s, 0.f);
    S[rr][k] = afac * rl*rl / (ssum[rr] + 1e-8f) + bfac * __expf(s - mmax[rr]) / dsum[rr];
  }
  float acc = 0.f;
  for (int kc = 0; kc < SEQ; kc += 128) {
    __syncthreads();
#pragma unroll
    for (int u = 0; u < 4; ++u) {
      int idx = t + u*256;
      int key = idx >> 3, dq = idx & 7;
      float4 v = *(const float4*)&qkv[((size_t)(b*SEQ + kc + key))*768 + 512 + h*32 + dq*4];
      ks[key][dq*4+0]=v.x; ks[key][dq*4+1]=v.y; ks[key][dq*4+2]=v.z; ks[key][dq*4+3]=v.w;
    }
    __syncthreads();
#pragma unroll 8
    for (int kk = 0; kk < 128; ++kk) acc += S[r][kc + kk] * ks[kk][dl];
  }
  o_out[((size_t)(b*SEQ + rblk*8 + r))*CDIM + h*32 + dl] = acc;
}

// ---------------- small 3x3 conv (SAME) ----------------
__global__ __launch_bounds__(256) void k_conv3(const float* __restrict__ in,
                                               const float* __restrict__ w,
                                               float* __restrict__ out, int Cin) {
  int oc = blockIdx.x;
  int p = blockIdx.y * 256 + threadIdx.x;
  int y = p >> 5, x = p & 31;
  float acc = 0.f;
  for (int c = 0; c < Cin; ++c) {
    const float* ip = in + c*1024;
    const float* wp = w + ((size_t)oc*Cin + c)*9;
#pragma unroll
    for (int i = 0; i < 3; ++i) {
      int yy = y + i - 1;
      if (yy < 0 || yy > 31) continue;
#pragma unroll
      for (int j = 0; j < 3; ++j) {
        int xx = x + j - 1;
        if (xx < 0 || xx > 31) continue;
        acc += ip[yy*32 + xx] * wp[i*3 + j];
      }
    }
  }
  out[oc*1024 + p] = acc;
}

// ---------------- LayerNorm over (C,H,W)=65536 + ReLU ----------------
__global__ __launch_bounds__(1024) void k_lnchw(const float* __restrict__ in,
                                                const float* __restrict__ g,
                                                const float* __restrict__ b,
                                                float* __restrict__ out) {
  __shared__ float red[1024];
  __shared__ float red2[1024];
  int t = threadIdx.x;
  float s = 0.f, sq = 0.f;
  for (int i = t; i < 65536; i += 1024) { float v = in[i]; s += v; sq += v*v; }
  red[t] = s; red2[t] = sq; __syncthreads();
  for (int o = 512; o > 0; o >>= 1) {
    if (t < o) { red[t] += red[t+o]; red2[t] += red2[t+o]; }
    __syncthreads();
  }
  float mean = red[0] * (1.f/65536.f);
  float var  = red2[0] * (1.f/65536.f) - mean*mean;
  float inv = rsqrtf(var + 1e-5f);
  for (int i = t; i < 65536; i += 1024) {
    float v = (in[i] - mean) * inv * g[i] + b[i];
    out[i] = fmaxf(v, 0.f);
  }
}

// ---------------- im2col^T of p (64,32,32) -> pmT[1024 px][576 k] bf16 ----------------
__global__ __launch_bounds__(576) void k_im2colT(const float* __restrict__ pin,
                                                 unsigned short* __restrict__ pmT) {
  int n = blockIdx.x, k = threadIdx.x;
  int c = k / 9, tap = k - c*9;
  int yy = (n >> 5) + tap/3 - 1, xx = (n & 31) + tap%3 - 1;
  float v = (yy >= 0 && yy < 32 && xx >= 0 && xx < 32) ? pin[c*1024 + yy*32 + xx] : 0.f;
  pmT[(size_t)n*576 + k] = (unsigned short)bf16rn(v);
}

__device__ __forceinline__ float gelu_exact(float x) {
  return 0.5f * x * (1.f + erff(x * 0.70710678118654752f));
}

// ------- MFMA cf conv (GEMM 18432x1024x576 bf16) + TVConv + GELU gate -> z -------
// block: 8 channel-pairs (c,c+1024) x 9 taps = 144 rows x 64 px; 4 waves, each owns 16 cols.
// LDS: A dbuf 2x18432B (swizzled), aliased by wgt[144][68]f32 after K-loop; y-halo tile after.
__global__ __launch_bounds__(256) void k_cf_tv_mfma(const float* __restrict__ cfw,
                                                    const unsigned short* __restrict__ pmT,
                                                    const float* __restrict__ y,
                                                    float* __restrict__ z) {
  __shared__ __align__(16) char s_lds[47616];
  char* Ab = s_lds;
  const int t = threadIdx.x;
  const int l = t & 63, w = t >> 6;
  const int n0 = blockIdx.x * 64;
  const int c0 = blockIdx.y * 8;

  f32x4 acc[9];
#pragma unroll
  for (int m = 0; m < 9; ++m) acc[m] = (f32x4){0.f, 0.f, 0.f, 0.f};

  float4 sreg[9];

  auto stage_load = [&](int kt) {
    const int k0 = kt * 64;
#pragma unroll
    for (int i = 0; i < 9; ++i) {
      int c = t + i*256;                 // 2304 chunks of 4 f32
      int r = c >> 4, s4 = c & 15;
      int grow = (r < 72) ? (c0*9 + r) : (9216 + c0*9 + (r - 72));
      sreg[i] = *(const float4*)(cfw + (size_t)grow*576 + k0 + s4*4);
    }
  };
  auto stage_write = [&](int buf) {
#pragma unroll
    for (int i = 0; i < 9; ++i) {
      int c = t + i*256;
      int r = c >> 4, s4 = c & 15;
      int byte = buf*18432 + r*128 + s4*8;
      byte ^= (r & 7) << 4;              // T2 swizzle: conflict-free b128 reads
      uint2 u;
      u.x = bf16rn(sreg[i].x) | (bf16rn(sreg[i].y) << 16);
      u.y = bf16rn(sreg[i].z) | (bf16rn(sreg[i].w) << 16);
      *(uint2*)(Ab + byte) = u;
    }
  };

  stage_load(0);
  stage_write(0);
  __syncthreads();

  const unsigned short* pB = pmT + (size_t)(n0 + w*16 + (l & 15))*576 + 8*(l >> 4);
  for (int kt = 0; kt < 9; ++kt) {
    if (kt < 8) stage_load(kt + 1);
    const int coff = (kt & 1) * 18432;
#pragma unroll
    for (int s = 0; s < 2; ++s) {
      const bf16x8 bv = *(const bf16x8*)(pB + kt*64 + s*32);
#pragma unroll
      for (int m = 0; m < 9; ++m) {
        int row = m*16 + (l & 15);
        int byte = coff + row*128 + s*64 + (l >> 4)*16;
        byte ^= (row & 7) << 4;
        bf16x8 av = *(const bf16x8*)(Ab + byte);
        acc[m] = __builtin_amdgcn_mfma_f32_16x16x32_bf16(av, bv, acc[m], 0, 0, 0);
      }
    }
    __syncthreads();
    if (kt < 8) { stage_write((kt + 1) & 1); __syncthreads(); }
  }

  // epilogue: acc -> wgt LDS (row = (ch-half)*9+tap local, col = px)
  float* W  = (float*)s_lds;             // [144][68]
  float* YL = (float*)(s_lds + 39168);   // [16][4][33]
#pragma unroll
  for (int m = 0; m < 9; ++m)
#pragma unroll
    for (int r = 0; r < 4; ++r)
      W[(m*16 + (l >> 4)*4 + r)*68 + w*16 + (l & 15)] = acc[m][r];
  __syncthreads();

  const int py0 = blockIdx.x * 2;
  const int p = t >> 5, lx = t & 31;
  for (int b = 0; b < 4; ++b) {
    if (b) __syncthreads();
#pragma unroll
    for (int i = 0; i < 8; ++i) {
      int idx = t + i*256;
      int chl = idx >> 7, rem = idx & 127;
      int ry = rem >> 5, px = rem & 31;
      int iy = py0 + ry - 1;
      int chG = (chl < 8) ? (c0 + chl) : (1024 + c0 + chl - 8);
      float v = (iy >= 0 && iy < 32) ? y[((size_t)b*2048 + chG)*1024 + iy*32 + px] : 0.f;
      YL[chl*132 + ry*33 + px] = v;
    }
    __syncthreads();
#pragma unroll
    for (int jj = 0; jj < 2; ++jj) {
      int nL = lx*2 + jj;
      int pyl = nL >> 5, pxl = nL & 31;
      float lo = 0.f, hi = 0.f;
#pragma unroll
      for (int i = 0; i < 9; ++i) {
        int rr = pyl + i/3;
        int ix = pxl + i%3 - 1;
        if (ix < 0 || ix > 31) continue;
        lo += W[(p*9 + i)*68 + nL]      * YL[p*132 + rr*33 + ix];
        hi += W[(72 + p*9 + i)*68 + nL] * YL[(8 + p)*132 + rr*33 + ix];
      }
      z[((size_t)b*1024 + c0 + p)*1024 + n0 + nL] = gelu_exact(lo) * hi;
    }
  }
}

// -------- pout GEMM: OUT[b][m][o] = xr[b][m][o] + sum_c z[b][c][m]*pw[o][c] --------
__global__ __launch_bounds__(256) void k_gemm_pout(const float* __restrict__ zbuf,
                                                   const float* __restrict__ pw,
                                                   const float* __restrict__ xr,
                                                   float* __restrict__ outp) {
  __shared__ float As[16][68];
  __shared__ float Bs[16][68];
  int b = blockIdx.z;
  int m0 = blockIdx.y * 64, n0 = blockIdx.x * 64;
  int t = threadIdx.x;
  const float* zp = zbuf + (size_t)b*1024*1024;
  int ty = t >> 4, tx = t & 15;
  int ak = t >> 4, am = (t & 15) * 4;
  int br = t >> 2, bk = (t & 3) * 4;
  float acc[4][4] = {};
  for (int k0 = 0; k0 < 1024; k0 += 16) {
    float4 av = *(const float4*)&zp[(size_t)(k0 + ak)*1024 + m0 + am];
    float4 bv = *(const float4*)&pw[(size_t)(n0 + br)*1024 + k0 + bk];
    As[ak][am+0]=av.x; As[ak][am+1]=av.y; As[ak][am+2]=av.z; As[ak][am+3]=av.w;
    Bs[bk+0][br]=bv.x; Bs[bk+1][br]=bv.y; Bs[bk+2][br]=bv.z; Bs[bk+3][br]=bv.w;
    __syncthreads();
#pragma unroll
    for (int kk = 0; kk < 16; ++kk) {
      float a[4], bb2[4];
#pragma unroll
      for (int i = 0; i < 4; ++i) a[i] = As[kk][ty*4+i];
#pragma unroll
      for (int j = 0; j < 4; ++j) bb2[j] = Bs[kk][tx*4+j];
#pragma unroll
      for (int i = 0; i < 4; ++i)
#pragma unroll
        for (int j = 0; j < 4; ++j) acc[i][j] += a[i]*bb2[j];
    }
    __syncthreads();
  }
#pragma unroll
  for (int i = 0; i < 4; ++i) {
    int m = m0 + ty*4 + i;
    size_t base = ((size_t)b*1024 + m)*256 + n0 + tx*4;
    float4 rv = *(const float4*)&xr[base];
    float4 ov;
    ov.x = acc[i][0] + rv.x; ov.y = acc[i][1] + rv.y;
    ov.z = acc[i][2] + rv.z; ov.w = acc[i][3] + rv.w;
    *(float4*)&outp[base] = ov;
  }
}

extern "C" void kernel_launch(void* const* d_in, const int* in_sizes, int n_in,
                              void* d_out, int out_size, void* d_ws, size_t ws_size,
                              hipStream_t stream) {
  (void)in_sizes; (void)n_in; (void)out_size; (void)ws_size;
  const float* x      = (const float*)d_in[0];
  const float* n1g    = (const float*)d_in[1];
  const float* n1b    = (const float*)d_in[2];
  const float* qkv_w  = (const float*)d_in[3];
  const float* alpha  = (const float*)d_in[4];
  const float* beta   = (const float*)d_in[5];
  const float* proj_w = (const float*)d_in[6];
  const float* proj_b = (const float*)d_in[7];
  const float* pin_w  = (const float*)d_in[8];
  const float* posi   = (const float*)d_in[9];
  const float* c0w    = (const float*)d_in[10];
  const float* l0g    = (const float*)d_in[11];
  const float* l0b    = (const float*)d_in[12];
  const float* c1w    = (const float*)d_in[13];
  const float* l1g    = (const float*)d_in[14];
  const float* l1b    = (const float*)d_in[15];
  const float* c2w    = (const float*)d_in[16];
  const float* l2g    = (const float*)d_in[17];
  const float* l2b    = (const float*)d_in[18];
  const float* cfw    = (const float*)d_in[19];
  const float* poutw  = (const float*)d_in[20];

  float* ws   = (float*)d_ws;
  float* h1   = ws + OFF_H1;
  float* qkvb = ws + OFF_QKV;
  float* ob   = ws + OFF_O;
  float* xr   = ws + OFF_XR;
  float* yb   = ws + OFF_Y;
  float* pA   = ws + OFF_PA;
  float* pB   = ws + OFF_PB;
  float* zb   = ws + OFF_Z;
  unsigned short* pmT = (unsigned short*)(ws + OFF_PMT);
  float* outp = (float*)d_out;

  // ASSA branch
  k_ln1<<<4096, 256, 0, stream>>>(x, n1g, n1b, h1);
  k_gemm_abt<<<dim3(12, 64, 1), 256, 0, stream>>>(h1, qkv_w, qkvb, nullptr, nullptr,
      256, 256, 256, 768, 0, 0, 0);
  k_attn<<<4096, 256, 0, stream>>>(qkvb, alpha, beta, ob);
  k_gemm_abt<<<dim3(4, 64, 1), 256, 0, stream>>>(ob, proj_w, xr, proj_b, x,
      256, 256, 256, 256, 0, 0, 0);
  // FRFN: project_in (per-batch), y[b][o][n]
  k_gemm_abt<<<dim3(16, 32, 4), 256, 0, stream>>>(pin_w, xr, yb, nullptr, nullptr,
      256, 256, 256, 1024, 0, 1024L*256, 2048L*1024);
  // posi-map conv/LN chain (pA/pB alias dead h1 region)
  k_conv3<<<dim3(64, 4), 256, 0, stream>>>(posi, c0w, pA, 4);
  k_lnchw<<<1, 1024, 0, stream>>>(pA, l0g, l0b, pB);
  k_conv3<<<dim3(64, 4), 256, 0, stream>>>(pB, c1w, pA, 64);
  k_lnchw<<<1, 1024, 0, stream>>>(pA, l1g, l1b, pB);
  k_conv3<<<dim3(64, 4), 256, 0, stream>>>(pB, c2w, pA, 64);
  k_lnchw<<<1, 1024, 0, stream>>>(pA, l2g, l2b, pB);
  k_im2colT<<<1024, 576, 0, stream>>>(pB, pmT);
  // MFMA cf conv GEMM + TVConv + gate -> z (aliases dead h1+qkv region)
  k_cf_tv_mfma<<<dim3(16, 128, 1), 256, 0, stream>>>(cfw, pmT, yb, zb);
  // project_out + residual -> d_out
  k_gemm_pout<<<dim3(4, 16, 4), 256, 0, stream>>>(zb, poutw, xr, outp);
}

// Round 12
// 672.994 us; speedup vs baseline: 1.8282x; 1.3049x over previous
//
#include <hip/hip_runtime.h>

#define SEQ 1024
#define CDIM 256

typedef short bf16x8 __attribute__((ext_vector_type(8)));
typedef float f32x4 __attribute__((ext_vector_type(4)));

// ---------------- workspace layout (float offsets, with lifetime aliasing) ----
// [0 .. 1,048,576)         h1 (phase1) | pA/pB (conv chain) | z (cf_tv..pout)
// [1,048,576 .. 4,194,304) qkv (phase1, dead after k_qkv2bf) | z tail
// [4,194,304 .. 5,242,880) o (attn)   | pmT (bf16, im2colT..cf_tv)
// [5,242,880 .. 6,291,456) xr (live to end)
// [6,291,456 .. 14,680,064) y
// [14,680,064 .. 16,252,928) Qb/Kb/Vt bf16 planes (qkv2bf..attn)
static const size_t OFF_H1  = 0;
static const size_t OFF_QKV = 1048576;
static const size_t OFF_Z   = 0;
static const size_t OFF_O   = 4194304;
static const size_t OFF_PMT = 4194304;
static const size_t OFF_XR  = 5242880;
static const size_t OFF_Y   = 6291456;
static const size_t OFF_PA  = 0;
static const size_t OFF_PB  = 65536;
static const size_t OFF_QB  = 14680064;   // 524288 floats each (1M u16)
static const size_t OFF_KB  = 15204352;
static const size_t OFF_VT  = 15728640;
// total = 16,252,928 floats = 65.0 MB

__device__ __forceinline__ unsigned bf16rn(float x) {
  unsigned u = __float_as_uint(x);
  return (u + 0x7fffu + ((u >> 16) & 1u)) >> 16;
}

// ---------------- LayerNorm over C=256, one block per row ----------------
__global__ __launch_bounds__(256) void k_ln1(const float* __restrict__ x,
                                             const float* __restrict__ g,
                                             const float* __restrict__ b,
                                             float* __restrict__ h1) {
  int row = blockIdx.x, t = threadIdx.x;
  __shared__ float red[256];
  float v = x[(size_t)row*CDIM + t];
  red[t] = v; __syncthreads();
  for (int o = 128; o > 0; o >>= 1) { if (t < o) red[t] += red[t+o]; __syncthreads(); }
  float mean = red[0] * (1.f/CDIM);
  __syncthreads();
  float d = v - mean;
  red[t] = d*d; __syncthreads();
  for (int o = 128; o > 0; o >>= 1) { if (t < o) red[t] += red[t+o]; __syncthreads(); }
  float var = red[0] * (1.f/CDIM);
  h1[(size_t)row*CDIM + t] = d * rsqrtf(var + 1e-5f) * g[t] + b[t];
}

// ---------------- GEMM: C[m][n] = sum_k A[m][k]*Bt[n][k] (+bias[n]) (+resid[m][n]) ----
__global__ __launch_bounds__(256) void k_gemm_abt(
    const float* __restrict__ A, const float* __restrict__ Bt, float* __restrict__ C,
    const float* __restrict__ bias, const float* __restrict__ resid,
    int K, int lda, int ldb, int ldc,
    long strideA, long strideB, long strideC) {
  __shared__ float As[16][68];
  __shared__ float Bs[16][68];
  const float* Ap = A + (size_t)blockIdx.z * strideA;
  const float* Bp = Bt + (size_t)blockIdx.z * strideB;
  float* Cp = C + (size_t)blockIdx.z * strideC;
  const float* Rp = resid ? (resid + (size_t)blockIdx.z * strideC) : nullptr;
  int m0 = blockIdx.y * 64, n0 = blockIdx.x * 64;
  int t = threadIdx.x;
  int lr = t >> 2, lk = (t & 3) * 4;
  int ty = t >> 4, tx = t & 15;
  float acc[4][4] = {};
  for (int k0 = 0; k0 < K; k0 += 16) {
    float4 av = *(const float4*)&Ap[(size_t)(m0 + lr)*lda + k0 + lk];
    float4 bv = *(const float4*)&Bp[(size_t)(n0 + lr)*ldb + k0 + lk];
    As[lk+0][lr] = av.x; As[lk+1][lr] = av.y; As[lk+2][lr] = av.z; As[lk+3][lr] = av.w;
    Bs[lk+0][lr] = bv.x; Bs[lk+1][lr] = bv.y; Bs[lk+2][lr] = bv.z; Bs[lk+3][lr] = bv.w;
    __syncthreads();
#pragma unroll
    for (int kk = 0; kk < 16; ++kk) {
      float a[4], bb[4];
#pragma unroll
      for (int i = 0; i < 4; ++i) a[i] = As[kk][ty*4+i];
#pragma unroll
      for (int j = 0; j < 4; ++j) bb[j] = Bs[kk][tx*4+j];
#pragma unroll
      for (int i = 0; i < 4; ++i)
#pragma unroll
        for (int j = 0; j < 4; ++j) acc[i][j] += a[i]*bb[j];
    }
    __syncthreads();
  }
#pragma unroll
  for (int i = 0; i < 4; ++i) {
    int m = m0 + ty*4 + i;
    float4 ov;
    float* o = &ov.x;
#pragma unroll
    for (int j = 0; j < 4; ++j) {
      float vv = acc[i][j];
      int n = n0 + tx*4 + j;
      if (bias) vv += bias[n];
      if (Rp)   vv += Rp[(size_t)m*ldc + n];
      o[j] = vv;
    }
    *(float4*)&Cp[(size_t)m*ldc + n0 + tx*4] = ov;
  }
}

// ---------------- qkv f32 -> bf16 planes: Qb/Kb[bh][n][32], Vt[bh][32][n] ----------------
__global__ __launch_bounds__(256) void k_qkv2bf(const float* __restrict__ qkv,
                                                unsigned short* __restrict__ Qb,
                                                unsigned short* __restrict__ Kb,
                                                unsigned short* __restrict__ Vt) {
  int row = blockIdx.x;           // b*1024 + n
  int t = threadIdx.x;            // h*32 + d
  int b = row >> 10, n = row & 1023;
  int h = t >> 5, d = t & 31;
  size_t bh = (size_t)(b*8 + h);
  float q = qkv[(size_t)row*768 + t];
  float k = qkv[(size_t)row*768 + 256 + t];
  float v = qkv[(size_t)row*768 + 512 + t];
  Qb[bh*32768 + n*32 + d] = (unsigned short)bf16rn(q);
  Kb[bh*32768 + n*32 + d] = (unsigned short)bf16rn(k);
  Vt[bh*32768 + d*1024 + n] = (unsigned short)bf16rn(v);
}

// ---------------- MFMA flash attention, dual sparse/dense blend ----------------
// grid 512 = bh(32) x qtile(16 of 64 rows); 4 waves x 16 q-rows; no barriers.
__global__ __launch_bounds__(256) void k_attn_mfma(const unsigned short* __restrict__ Qb,
                                                   const unsigned short* __restrict__ Kb,
                                                   const unsigned short* __restrict__ Vt,
                                                   const float* __restrict__ alpha,
                                                   const float* __restrict__ beta,
                                                   float* __restrict__ o_out) {
  __shared__ __align__(16) char Pl[16384];   // [wave][{dn,sp}][16q][64k] bf16, swizzled
  const int bh = blockIdx.x >> 4, qt = blockIdx.x & 15;
  const int b = bh >> 3, h = bh & 7;
  const int t = threadIdx.x;
  const int l = t & 63, w = t >> 6;
  const float scale = 0.17677669529663687f;

  const unsigned short* Qp = Qb + (size_t)bh*32768;
  const unsigned short* Kp = Kb + (size_t)bh*32768;
  const unsigned short* Vp = Vt + (size_t)bh*32768;

  // Q fragment: row = l&15 (wave-local), k-elems (l>>4)*8..+7
  const int qrowA = qt*64 + w*16 + (l & 15);
  const bf16x8 a_q = *(const bf16x8*)(Qp + (size_t)qrowA*32 + (l >> 4)*8);

  f32x4 acc_dn[2] = {(f32x4){0,0,0,0}, (f32x4){0,0,0,0}};
  f32x4 acc_sp[2] = {(f32x4){0,0,0,0}, (f32x4){0,0,0,0}};
  float m[4]  = {-1e30f, -1e30f, -1e30f, -1e30f};
  float ds[4] = {0.f, 0.f, 0.f, 0.f};
  float ss[4] = {0.f, 0.f, 0.f, 0.f};

  const int pbase = w << 12;                 // 4 KB per wave
  const int wq = (l >> 4) * 4;               // D-layout q-row base for this lane

  for (int kt = 0; kt < 16; ++kt) {
    // ---- QK^T: 4 MFMAs (K = hd = 32 in one shot) ----
    f32x4 s[4];
#pragma unroll
    for (int kf = 0; kf < 4; ++kf) {
      const bf16x8 bk = *(const bf16x8*)(Kp + (size_t)(kt*64 + kf*16 + (l & 15))*32 + (l >> 4)*8);
      s[kf] = __builtin_amdgcn_mfma_f32_16x16x32_bf16(a_q, bk, (f32x4){0,0,0,0}, 0, 0, 0);
    }
#pragma unroll
    for (int kf = 0; kf < 4; ++kf)
#pragma unroll
      for (int r = 0; r < 4; ++r) s[kf][r] *= scale;

    // ---- online stats + P matrices ----
#pragma unroll
    for (int r = 0; r < 4; ++r) {
      float mx = fmaxf(fmaxf(s[0][r], s[1][r]), fmaxf(s[2][r], s[3][r]));
      mx = fmaxf(mx, __shfl_xor(mx, 1));
      mx = fmaxf(mx, __shfl_xor(mx, 2));
      mx = fmaxf(mx, __shfl_xor(mx, 4));
      mx = fmaxf(mx, __shfl_xor(mx, 8));
      float mn = fmaxf(m[r], mx);
      float sc = __expf(m[r] - mn);
      m[r] = mn;
      acc_dn[0][r] *= sc; acc_dn[1][r] *= sc;
      float sum_d = 0.f, sum_s = 0.f;
      const int q = wq + r;
#pragma unroll
      for (int kf = 0; kf < 4; ++kf) {
        float sv = s[kf][r];
        float e = __expf(sv - mn);
        float rl = fmaxf(sv, 0.f); rl *= rl;
        sum_d += e; sum_s += rl;
        int byte = pbase + q*128 + (kf*16 + (l & 15))*2;
        byte ^= (q & 7) << 4;
        *(unsigned short*)(Pl + byte)        = (unsigned short)bf16rn(e);
        *(unsigned short*)(Pl + 2048 + byte) = (unsigned short)bf16rn(rl);
      }
      sum_d += __shfl_xor(sum_d, 1); sum_s += __shfl_xor(sum_s, 1);
      sum_d += __shfl_xor(sum_d, 2); sum_s += __shfl_xor(sum_s, 2);
      sum_d += __shfl_xor(sum_d, 4); sum_s += __shfl_xor(sum_s, 4);
      sum_d += __shfl_xor(sum_d, 8); sum_s += __shfl_xor(sum_s, 8);
      ds[r] = ds[r]*sc + sum_d;
      ss[r] += sum_s;
    }

    // ---- PV: 2 key-chunks x {dn,sp} x 2 d-frags ----
#pragma unroll
    for (int c = 0; c < 2; ++c) {
      int rbyte = pbase + (l & 15)*128 + c*64 + (l >> 4)*16;
      rbyte ^= (l & 7) << 4;
      const bf16x8 a_pd = *(const bf16x8*)(Pl + rbyte);
      const bf16x8 a_ps = *(const bf16x8*)(Pl + 2048 + rbyte);
#pragma unroll
      for (int df = 0; df < 2; ++df) {
        const bf16x8 bv = *(const bf16x8*)(Vp + (size_t)(df*16 + (l & 15))*1024
                                              + kt*64 + c*32 + (l >> 4)*8);
        acc_dn[df] = __builtin_amdgcn_mfma_f32_16x16x32_bf16(a_pd, bv, acc_dn[df], 0, 0, 0);
        acc_sp[df] = __builtin_amdgcn_mfma_f32_16x16x32_bf16(a_ps, bv, acc_sp[df], 0, 0, 0);
      }
    }
  }

  // ---- blend + store ----
  float a_s = 1.f/(1.f + __expf(-alpha[0]));
  float b_s = 1.f/(1.f + __expf(-beta[0]));
  float wsn = a_s + b_s + 1e-8f;
  float afac = a_s/wsn, bfac = b_s/wsn;
#pragma unroll
  for (int r = 0; r < 4; ++r) {
    int qrow = qt*64 + w*16 + wq + r;
    float is = afac / (ss[r] + 1e-8f);
    float id = bfac / ds[r];
    size_t base = ((size_t)(b*SEQ + qrow))*CDIM + h*32 + (l & 15);
#pragma unroll
    for (int df = 0; df < 2; ++df)
      o_out[base + df*16] = acc_sp[df][r]*is + acc_dn[df][r]*id;
  }
}

// ---------------- small 3x3 conv (SAME) ----------------
__global__ __launch_bounds__(256) void k_conv3(const float* __restrict__ in,
                                               const float* __restrict__ w,
                                               float* __restrict__ out, int Cin) {
  int oc = blockIdx.x;
  int p = blockIdx.y * 256 + threadIdx.x;
  int y = p >> 5, x = p & 31;
  float acc = 0.f;
  for (int c = 0; c < Cin; ++c) {
    const float* ip = in + c*1024;
    const float* wp = w + ((size_t)oc*Cin + c)*9;
#pragma unroll
    for (int i = 0; i < 3; ++i) {
      int yy = y + i - 1;
      if (yy < 0 || yy > 31) continue;
#pragma unroll
      for (int j = 0; j < 3; ++j) {
        int xx = x + j - 1;
        if (xx < 0 || xx > 31) continue;
        acc += ip[yy*32 + xx] * wp[i*3 + j];
      }
    }
  }
  out[oc*1024 + p] = acc;
}

// ---------------- LayerNorm over (C,H,W)=65536 + ReLU ----------------
__global__ __launch_bounds__(1024) void k_lnchw(const float* __restrict__ in,
                                                const float* __restrict__ g,
                                                const float* __restrict__ b,
                                                float* __restrict__ out) {
  __shared__ float red[1024];
  __shared__ float red2[1024];
  int t = threadIdx.x;
  float s = 0.f, sq = 0.f;
  for (int i = t; i < 65536; i += 1024) { float v = in[i]; s += v; sq += v*v; }
  red[t] = s; red2[t] = sq; __syncthreads();
  for (int o = 512; o > 0; o >>= 1) {
    if (t < o) { red[t] += red[t+o]; red2[t] += red2[t+o]; }
    __syncthreads();
  }
  float mean = red[0] * (1.f/65536.f);
  float var  = red2[0] * (1.f/65536.f) - mean*mean;
  float inv = rsqrtf(var + 1e-5f);
  for (int i = t; i < 65536; i += 1024) {
    float v = (in[i] - mean) * inv * g[i] + b[i];
    out[i] = fmaxf(v, 0.f);
  }
}

// ---------------- im2col^T of p (64,32,32) -> pmT[1024 px][576 k] bf16 ----------------
__global__ __launch_bounds__(576) void k_im2colT(const float* __restrict__ pin,
                                                 unsigned short* __restrict__ pmT) {
  int n = blockIdx.x, k = threadIdx.x;
  int c = k / 9, tap = k - c*9;
  int yy = (n >> 5) + tap/3 - 1, xx = (n & 31) + tap%3 - 1;
  float v = (yy >= 0 && yy < 32 && xx >= 0 && xx < 32) ? pin[c*1024 + yy*32 + xx] : 0.f;
  pmT[(size_t)n*576 + k] = (unsigned short)bf16rn(v);
}

__device__ __forceinline__ float gelu_exact(float x) {
  return 0.5f * x * (1.f + erff(x * 0.70710678118654752f));
}

// ------- MFMA cf conv (GEMM 18432x1024x576 bf16) + TVConv + GELU gate -> z -------
__global__ __launch_bounds__(256) void k_cf_tv_mfma(const float* __restrict__ cfw,
                                                    const unsigned short* __restrict__ pmT,
                                                    const float* __restrict__ y,
                                                    float* __restrict__ z) {
  __shared__ __align__(16) char s_lds[47616];
  char* Ab = s_lds;
  const int t = threadIdx.x;
  const int l = t & 63, w = t >> 6;
  const int n0 = blockIdx.x * 64;
  const int c0 = blockIdx.y * 8;

  f32x4 acc[9];
#pragma unroll
  for (int m = 0; m < 9; ++m) acc[m] = (f32x4){0.f, 0.f, 0.f, 0.f};

  float4 sreg[9];

  auto stage_load = [&](int kt) {
    const int k0 = kt * 64;
#pragma unroll
    for (int i = 0; i < 9; ++i) {
      int c = t + i*256;
      int r = c >> 4, s4 = c & 15;
      int grow = (r < 72) ? (c0*9 + r) : (9216 + c0*9 + (r - 72));
      sreg[i] = *(const float4*)(cfw + (size_t)grow*576 + k0 + s4*4);
    }
  };
  auto stage_write = [&](int buf) {
#pragma unroll
    for (int i = 0; i < 9; ++i) {
      int c = t + i*256;
      int r = c >> 4, s4 = c & 15;
      int byte = buf*18432 + r*128 + s4*8;
      byte ^= (r & 7) << 4;
      uint2 u;
      u.x = bf16rn(sreg[i].x) | (bf16rn(sreg[i].y) << 16);
      u.y = bf16rn(sreg[i].z) | (bf16rn(sreg[i].w) << 16);
      *(uint2*)(Ab + byte) = u;
    }
  };

  stage_load(0);
  stage_write(0);
  __syncthreads();

  const unsigned short* pB = pmT + (size_t)(n0 + w*16 + (l & 15))*576 + 8*(l >> 4);
  for (int kt = 0; kt < 9; ++kt) {
    if (kt < 8) stage_load(kt + 1);
    const int coff = (kt & 1) * 18432;
#pragma unroll
    for (int s = 0; s < 2; ++s) {
      const bf16x8 bv = *(const bf16x8*)(pB + kt*64 + s*32);
#pragma unroll
      for (int m = 0; m < 9; ++m) {
        int row = m*16 + (l & 15);
        int byte = coff + row*128 + s*64 + (l >> 4)*16;
        byte ^= (row & 7) << 4;
        bf16x8 av = *(const bf16x8*)(Ab + byte);
        acc[m] = __builtin_amdgcn_mfma_f32_16x16x32_bf16(av, bv, acc[m], 0, 0, 0);
      }
    }
    __syncthreads();
    if (kt < 8) { stage_write((kt + 1) & 1); __syncthreads(); }
  }

  float* W  = (float*)s_lds;             // [144][68]
  float* YL = (float*)(s_lds + 39168);   // [16][4][33]
#pragma unroll
  for (int m = 0; m < 9; ++m)
#pragma unroll
    for (int r = 0; r < 4; ++r)
      W[(m*16 + (l >> 4)*4 + r)*68 + w*16 + (l & 15)] = acc[m][r];
  __syncthreads();

  const int py0 = blockIdx.x * 2;
  const int p = t >> 5, lx = t & 31;
  for (int b = 0; b < 4; ++b) {
    if (b) __syncthreads();
#pragma unroll
    for (int i = 0; i < 8; ++i) {
      int idx = t + i*256;
      int chl = idx >> 7, rem = idx & 127;
      int ry = rem >> 5, px = rem & 31;
      int iy = py0 + ry - 1;
      int chG = (chl < 8) ? (c0 + chl) : (1024 + c0 + chl - 8);
      float v = (iy >= 0 && iy < 32) ? y[((size_t)b*2048 + chG)*1024 + iy*32 + px] : 0.f;
      YL[chl*132 + ry*33 + px] = v;
    }
    __syncthreads();
#pragma unroll
    for (int jj = 0; jj < 2; ++jj) {
      int nL = lx*2 + jj;
      int pyl = nL >> 5, pxl = nL & 31;
      float lo = 0.f, hi = 0.f;
#pragma unroll
      for (int i = 0; i < 9; ++i) {
        int rr = pyl + i/3;
        int ix = pxl + i%3 - 1;
        if (ix < 0 || ix > 31) continue;
        lo += W[(p*9 + i)*68 + nL]      * YL[p*132 + rr*33 + ix];
        hi += W[(72 + p*9 + i)*68 + nL] * YL[(8 + p)*132 + rr*33 + ix];
      }
      z[((size_t)b*1024 + c0 + p)*1024 + n0 + nL] = gelu_exact(lo) * hi;
    }
  }
}

// -------- pout GEMM: OUT[b][m][o] = xr[b][m][o] + sum_c z[b][c][m]*pw[o][c] --------
__global__ __launch_bounds__(256) void k_gemm_pout(const float* __restrict__ zbuf,
                                                   const float* __restrict__ pw,
                                                   const float* __restrict__ xr,
                                                   float* __restrict__ outp) {
  __shared__ float As[16][68];
  __shared__ float Bs[16][68];
  int b = blockIdx.z;
  int m0 = blockIdx.y * 64, n0 = blockIdx.x * 64;
  int t = threadIdx.x;
  const float* zp = zbuf + (size_t)b*1024*1024;
  int ty = t >> 4, tx = t & 15;
  int ak = t >> 4, am = (t & 15) * 4;
  int br = t >> 2, bk = (t & 3) * 4;
  float acc[4][4] = {};
  for (int k0 = 0; k0 < 1024; k0 += 16) {
    float4 av = *(const float4*)&zp[(size_t)(k0 + ak)*1024 + m0 + am];
    float4 bv = *(const float4*)&pw[(size_t)(n0 + br)*1024 + k0 + bk];
    As[ak][am+0]=av.x; As[ak][am+1]=av.y; As[ak][am+2]=av.z; As[ak][am+3]=av.w;
    Bs[bk+0][br]=bv.x; Bs[bk+1][br]=bv.y; Bs[bk+2][br]=bv.z; Bs[bk+3][br]=bv.w;
    __syncthreads();
#pragma unroll
    for (int kk = 0; kk < 16; ++kk) {
      float a[4], bb2[4];
#pragma unroll
      for (int i = 0; i < 4; ++i) a[i] = As[kk][ty*4+i];
#pragma unroll
      for (int j = 0; j < 4; ++j) bb2[j] = Bs[kk][tx*4+j];
#pragma unroll
      for (int i = 0; i < 4; ++i)
#pragma unroll
        for (int j = 0; j < 4; ++j) acc[i][j] += a[i]*bb2[j];
    }
    __syncthreads();
  }
#pragma unroll
  for (int i = 0; i < 4; ++i) {
    int m = m0 + ty*4 + i;
    size_t base = ((size_t)b*1024 + m)*256 + n0 + tx*4;
    float4 rv = *(const float4*)&xr[base];
    float4 ov;
    ov.x = acc[i][0] + rv.x; ov.y = acc[i][1] + rv.y;
    ov.z = acc[i][2] + rv.z; ov.w = acc[i][3] + rv.w;
    *(float4*)&outp[base] = ov;
  }
}

extern "C" void kernel_launch(void* const* d_in, const int* in_sizes, int n_in,
                              void* d_out, int out_size, void* d_ws, size_t ws_size,
                              hipStream_t stream) {
  (void)in_sizes; (void)n_in; (void)out_size; (void)ws_size;
  const float* x      = (const float*)d_in[0];
  const float* n1g    = (const float*)d_in[1];
  const float* n1b    = (const float*)d_in[2];
  const float* qkv_w  = (const float*)d_in[3];
  const float* alpha  = (const float*)d_in[4];
  const float* beta   = (const float*)d_in[5];
  const float* proj_w = (const float*)d_in[6];
  const float* proj_b = (const float*)d_in[7];
  const float* pin_w  = (const float*)d_in[8];
  const float* posi   = (const float*)d_in[9];
  const float* c0w    = (const float*)d_in[10];
  const float* l0g    = (const float*)d_in[11];
  const float* l0b    = (const float*)d_in[12];
  const float* c1w    = (const float*)d_in[13];
  const float* l1g    = (const float*)d_in[14];
  const float* l1b    = (const float*)d_in[15];
  const float* c2w    = (const float*)d_in[16];
  const float* l2g    = (const float*)d_in[17];
  const float* l2b    = (const float*)d_in[18];
  const float* cfw    = (const float*)d_in[19];
  const float* poutw  = (const float*)d_in[20];

  float* ws   = (float*)d_ws;
  float* h1   = ws + OFF_H1;
  float* qkvb = ws + OFF_QKV;
  float* ob   = ws + OFF_O;
  float* xr   = ws + OFF_XR;
  float* yb   = ws + OFF_Y;
  float* pA   = ws + OFF_PA;
  float* pB   = ws + OFF_PB;
  float* zb   = ws + OFF_Z;
  unsigned short* pmT = (unsigned short*)(ws + OFF_PMT);
  unsigned short* Qbp = (unsigned short*)(ws + OFF_QB);
  unsigned short* Kbp = (unsigned short*)(ws + OFF_KB);
  unsigned short* Vtp = (unsigned short*)(ws + OFF_VT);
  float* outp = (float*)d_out;

  // ASSA branch
  k_ln1<<<4096, 256, 0, stream>>>(x, n1g, n1b, h1);
  k_gemm_abt<<<dim3(12, 64, 1), 256, 0, stream>>>(h1, qkv_w, qkvb, nullptr, nullptr,
      256, 256, 256, 768, 0, 0, 0);
  k_qkv2bf<<<4096, 256, 0, stream>>>(qkvb, Qbp, Kbp, Vtp);
  k_attn_mfma<<<512, 256, 0, stream>>>(Qbp, Kbp, Vtp, alpha, beta, ob);
  k_gemm_abt<<<dim3(4, 64, 1), 256, 0, stream>>>(ob, proj_w, xr, proj_b, x,
      256, 256, 256, 256, 0, 0, 0);
  // FRFN: project_in (per-batch), y[b][o][n]
  k_gemm_abt<<<dim3(16, 32, 4), 256, 0, stream>>>(pin_w, xr, yb, nullptr, nullptr,
      256, 256, 256, 1024, 0, 1024L*256, 2048L*1024);
  // posi-map conv/LN chain (pA/pB alias dead h1 region)
  k_conv3<<<dim3(64, 4), 256, 0, stream>>>(posi, c0w, pA, 4);
  k_lnchw<<<1, 1024, 0, stream>>>(pA, l0g, l0b, pB);
  k_conv3<<<dim3(64, 4), 256, 0, stream>>>(pB, c1w, pA, 64);
  k_lnchw<<<1, 1024, 0, stream>>>(pA, l1g, l1b, pB);
  k_conv3<<<dim3(64, 4), 256, 0, stream>>>(pB, c2w, pA, 64);
  k_lnchw<<<1, 1024, 0, stream>>>(pA, l2g, l2b, pB);
  k_im2colT<<<1024, 576, 0, stream>>>(pB, pmT);
  // MFMA cf conv GEMM + TVConv + gate -> z (aliases dead h1+qkv region)
  k_cf_tv_mfma<<<dim3(16, 128, 1), 256, 0, stream>>>(cfw, pmT, yb, zb);
  // project_out + residual -> d_out
  k_gemm_pout<<<dim3(4, 16, 4), 256, 0, stream>>>(zb, poutw, xr, outp);
}

// Round 13
// 660.827 us; speedup vs baseline: 1.8618x; 1.0184x over previous
//
#include <hip/hip_runtime.h>

#define SEQ 1024
#define CDIM 256

typedef short bf16x8 __attribute__((ext_vector_type(8)));
typedef float f32x4 __attribute__((ext_vector_type(4)));

// ---------------- workspace layout (float offsets, with lifetime aliasing) ----
// [0 .. 1,048,576)         h1b (phase1) | pA/pB (conv chain) | z (cf_tv..pout)
// [1,048,576 .. 4,194,304) qkv (phase1, dead after k_qkv2bf) | z tail
// [4,194,304 .. 5,242,880) o (attn)   | pmT (bf16, im2colT..cf_tv)
// [5,242,880 .. 6,291,456) xr (live to end)
// [6,291,456 .. 14,680,064) y
// [14,680,064 .. 16,252,928) Qb/Kb/Vt bf16 planes (qkv2bf..attn)
// [16,252,928 ..] qkv_wb, pin_wb, xrb (bf16)
static const size_t OFF_H1  = 0;
static const size_t OFF_QKV = 1048576;
static const size_t OFF_Z   = 0;
static const size_t OFF_O   = 4194304;
static const size_t OFF_PMT = 4194304;
static const size_t OFF_XR  = 5242880;
static const size_t OFF_Y   = 6291456;
static const size_t OFF_PA  = 0;
static const size_t OFF_PB  = 65536;
static const size_t OFF_QB  = 14680064;   // 524288 floats each (1M u16)
static const size_t OFF_KB  = 15204352;
static const size_t OFF_VT  = 15728640;
static const size_t OFF_QWB = 16252928;   // 768*256 u16  = 98304 floats
static const size_t OFF_PWB = 16351232;   // 2048*256 u16 = 262144 floats
static const size_t OFF_XRB = 16613376;   // 4096*256 u16 = 524288 floats
// total = 17,137,664 floats = 68.6 MB

__device__ __forceinline__ unsigned bf16rn(float x) {
  unsigned u = __float_as_uint(x);
  return (u + 0x7fffu + ((u >> 16) & 1u)) >> 16;
}

// ---------------- generic f32 -> bf16 ----------------
__global__ __launch_bounds__(256) void k_w2bf(const float* __restrict__ in,
                                              unsigned short* __restrict__ out, int n) {
  int i = blockIdx.x*256 + threadIdx.x;
  if (i < n) out[i] = (unsigned short)bf16rn(in[i]);
}

// ---------------- LayerNorm over C=256, one block per row -> bf16 ----------------
__global__ __launch_bounds__(256) void k_ln1(const float* __restrict__ x,
                                             const float* __restrict__ g,
                                             const float* __restrict__ b,
                                             unsigned short* __restrict__ h1b) {
  int row = blockIdx.x, t = threadIdx.x;
  __shared__ float red[256];
  float v = x[(size_t)row*CDIM + t];
  red[t] = v; __syncthreads();
  for (int o = 128; o > 0; o >>= 1) { if (t < o) red[t] += red[t+o]; __syncthreads(); }
  float mean = red[0] * (1.f/CDIM);
  __syncthreads();
  float d = v - mean;
  red[t] = d*d; __syncthreads();
  for (int o = 128; o > 0; o >>= 1) { if (t < o) red[t] += red[t+o]; __syncthreads(); }
  float var = red[0] * (1.f/CDIM);
  h1b[(size_t)row*CDIM + t] = (unsigned short)bf16rn(d * rsqrtf(var + 1e-5f) * g[t] + b[t]);
}

// ---------------- bf16 MFMA GEMM: C[m][n] = sum_k A[m][k]*Bt[n][k], K=256 ----------------
// block 256 thr = 4 waves; tile 64x64; wave w: rows +w*16, all 64 cols; no LDS, no barriers.
__global__ __launch_bounds__(256) void k_gemm_bf(
    const unsigned short* __restrict__ A, const unsigned short* __restrict__ Bt,
    float* __restrict__ C, int ldc, long strideB, long strideC) {
  const int t = threadIdx.x, l = t & 63, w = t >> 6;
  const int mw = blockIdx.y*64 + w*16;
  const int n0 = blockIdx.x*64;
  const unsigned short* Bp = Bt + (size_t)blockIdx.z * strideB;
  float* Cp = C + (size_t)blockIdx.z * strideC;
  f32x4 acc[4];
#pragma unroll
  for (int nf = 0; nf < 4; ++nf) acc[nf] = (f32x4){0.f,0.f,0.f,0.f};
  const unsigned short* arow = A  + (size_t)(mw + (l & 15))*256 + (l >> 4)*8;
  const unsigned short* brow = Bp + (size_t)(n0 + (l & 15))*256 + (l >> 4)*8;
#pragma unroll
  for (int ks = 0; ks < 8; ++ks) {
    const bf16x8 a = *(const bf16x8*)(arow + ks*32);
#pragma unroll
    for (int nf = 0; nf < 4; ++nf) {
      const bf16x8 b = *(const bf16x8*)(brow + nf*16*256 + ks*32);
      acc[nf] = __builtin_amdgcn_mfma_f32_16x16x32_bf16(a, b, acc[nf], 0, 0, 0);
    }
  }
#pragma unroll
  for (int nf = 0; nf < 4; ++nf)
#pragma unroll
    for (int j = 0; j < 4; ++j)
      Cp[(size_t)(mw + (l >> 4)*4 + j)*ldc + n0 + nf*16 + (l & 15)] = acc[nf][j];
}

// ---------------- GEMM: C[m][n] = sum_k A[m][k]*Bt[n][k] (+bias[n]) (+resid[m][n]) ----
__global__ __launch_bounds__(256) void k_gemm_abt(
    const float* __restrict__ A, const float* __restrict__ Bt, float* __restrict__ C,
    const float* __restrict__ bias, const float* __restrict__ resid,
    int K, int lda, int ldb, int ldc,
    long strideA, long strideB, long strideC,
    unsigned short* __restrict__ Cb) {
  __shared__ float As[16][68];
  __shared__ float Bs[16][68];
  const float* Ap = A + (size_t)blockIdx.z * strideA;
  const float* Bp = Bt + (size_t)blockIdx.z * strideB;
  float* Cp = C + (size_t)blockIdx.z * strideC;
  const float* Rp = resid ? (resid + (size_t)blockIdx.z * strideC) : nullptr;
  int m0 = blockIdx.y * 64, n0 = blockIdx.x * 64;
  int t = threadIdx.x;
  int lr = t >> 2, lk = (t & 3) * 4;
  int ty = t >> 4, tx = t & 15;
  float acc[4][4] = {};
  for (int k0 = 0; k0 < K; k0 += 16) {
    float4 av = *(const float4*)&Ap[(size_t)(m0 + lr)*lda + k0 + lk];
    float4 bv = *(const float4*)&Bp[(size_t)(n0 + lr)*ldb + k0 + lk];
    As[lk+0][lr] = av.x; As[lk+1][lr] = av.y; As[lk+2][lr] = av.z; As[lk+3][lr] = av.w;
    Bs[lk+0][lr] = bv.x; Bs[lk+1][lr] = bv.y; Bs[lk+2][lr] = bv.z; Bs[lk+3][lr] = bv.w;
    __syncthreads();
#pragma unroll
    for (int kk = 0; kk < 16; ++kk) {
      float a[4], bb[4];
#pragma unroll
      for (int i = 0; i < 4; ++i) a[i] = As[kk][ty*4+i];
#pragma unroll
      for (int j = 0; j < 4; ++j) bb[j] = Bs[kk][tx*4+j];
#pragma unroll
      for (int i = 0; i < 4; ++i)
#pragma unroll
        for (int j = 0; j < 4; ++j) acc[i][j] += a[i]*bb[j];
    }
    __syncthreads();
  }
#pragma unroll
  for (int i = 0; i < 4; ++i) {
    int m = m0 + ty*4 + i;
    float4 ov;
    float* o = &ov.x;
#pragma unroll
    for (int j = 0; j < 4; ++j) {
      float vv = acc[i][j];
      int n = n0 + tx*4 + j;
      if (bias) vv += bias[n];
      if (Rp)   vv += Rp[(size_t)m*ldc + n];
      o[j] = vv;
    }
    *(float4*)&Cp[(size_t)m*ldc + n0 + tx*4] = ov;
    if (Cb) {
#pragma unroll
      for (int j = 0; j < 4; ++j)
        Cb[(size_t)m*ldc + n0 + tx*4 + j] = (unsigned short)bf16rn(o[j]);
    }
  }
}

// ---------------- qkv f32 -> bf16 planes: Qb/Kb[bh][n][32], Vt[bh][32][n] ----------------
__global__ __launch_bounds__(256) void k_qkv2bf(const float* __restrict__ qkv,
                                                unsigned short* __restrict__ Qb,
                                                unsigned short* __restrict__ Kb,
                                                unsigned short* __restrict__ Vt) {
  int row = blockIdx.x;           // b*1024 + n
  int t = threadIdx.x;            // h*32 + d
  int b = row >> 10, n = row & 1023;
  int h = t >> 5, d = t & 31;
  size_t bh = (size_t)(b*8 + h);
  float q = qkv[(size_t)row*768 + t];
  float k = qkv[(size_t)row*768 + 256 + t];
  float v = qkv[(size_t)row*768 + 512 + t];
  Qb[bh*32768 + n*32 + d] = (unsigned short)bf16rn(q);
  Kb[bh*32768 + n*32 + d] = (unsigned short)bf16rn(k);
  Vt[bh*32768 + d*1024 + n] = (unsigned short)bf16rn(v);
}

// ---------------- MFMA flash attention, dual sparse/dense blend ----------------
__global__ __launch_bounds__(256) void k_attn_mfma(const unsigned short* __restrict__ Qb,
                                                   const unsigned short* __restrict__ Kb,
                                                   const unsigned short* __restrict__ Vt,
                                                   const float* __restrict__ alpha,
                                                   const float* __restrict__ beta,
                                                   float* __restrict__ o_out) {
  __shared__ __align__(16) char Pl[16384];
  const int bh = blockIdx.x >> 4, qt = blockIdx.x & 15;
  const int b = bh >> 3, h = bh & 7;
  const int t = threadIdx.x;
  const int l = t & 63, w = t >> 6;
  const float scale = 0.17677669529663687f;

  const unsigned short* Qp = Qb + (size_t)bh*32768;
  const unsigned short* Kp = Kb + (size_t)bh*32768;
  const unsigned short* Vp = Vt + (size_t)bh*32768;

  const int qrowA = qt*64 + w*16 + (l & 15);
  const bf16x8 a_q = *(const bf16x8*)(Qp + (size_t)qrowA*32 + (l >> 4)*8);

  f32x4 acc_dn[2] = {(f32x4){0,0,0,0}, (f32x4){0,0,0,0}};
  f32x4 acc_sp[2] = {(f32x4){0,0,0,0}, (f32x4){0,0,0,0}};
  float m[4]  = {-1e30f, -1e30f, -1e30f, -1e30f};
  float ds[4] = {0.f, 0.f, 0.f, 0.f};
  float ss[4] = {0.f, 0.f, 0.f, 0.f};

  const int pbase = w << 12;
  const int wq = (l >> 4) * 4;

  for (int kt = 0; kt < 16; ++kt) {
    f32x4 s[4];
#pragma unroll
    for (int kf = 0; kf < 4; ++kf) {
      const bf16x8 bk = *(const bf16x8*)(Kp + (size_t)(kt*64 + kf*16 + (l & 15))*32 + (l >> 4)*8);
      s[kf] = __builtin_amdgcn_mfma_f32_16x16x32_bf16(a_q, bk, (f32x4){0,0,0,0}, 0, 0, 0);
    }
#pragma unroll
    for (int kf = 0; kf < 4; ++kf)
#pragma unroll
      for (int r = 0; r < 4; ++r) s[kf][r] *= scale;

#pragma unroll
    for (int r = 0; r < 4; ++r) {
      float mx = fmaxf(fmaxf(s[0][r], s[1][r]), fmaxf(s[2][r], s[3][r]));
      mx = fmaxf(mx, __shfl_xor(mx, 1));
      mx = fmaxf(mx, __shfl_xor(mx, 2));
      mx = fmaxf(mx, __shfl_xor(mx, 4));
      mx = fmaxf(mx, __shfl_xor(mx, 8));
      float mn = fmaxf(m[r], mx);
      float sc = __expf(m[r] - mn);
      m[r] = mn;
      acc_dn[0][r] *= sc; acc_dn[1][r] *= sc;
      float sum_d = 0.f, sum_s = 0.f;
      const int q = wq + r;
#pragma unroll
      for (int kf = 0; kf < 4; ++kf) {
        float sv = s[kf][r];
        float e = __expf(sv - mn);
        float rl = fmaxf(sv, 0.f); rl *= rl;
        sum_d += e; sum_s += rl;
        int byte = pbase + q*128 + (kf*16 + (l & 15))*2;
        byte ^= (q & 7) << 4;
        *(unsigned short*)(Pl + byte)        = (unsigned short)bf16rn(e);
        *(unsigned short*)(Pl + 2048 + byte) = (unsigned short)bf16rn(rl);
      }
      sum_d += __shfl_xor(sum_d, 1); sum_s += __shfl_xor(sum_s, 1);
      sum_d += __shfl_xor(sum_d, 2); sum_s += __shfl_xor(sum_s, 2);
      sum_d += __shfl_xor(sum_d, 4); sum_s += __shfl_xor(sum_s, 4);
      sum_d += __shfl_xor(sum_d, 8); sum_s += __shfl_xor(sum_s, 8);
      ds[r] = ds[r]*sc + sum_d;
      ss[r] += sum_s;
    }

#pragma unroll
    for (int c = 0; c < 2; ++c) {
      int rbyte = pbase + (l & 15)*128 + c*64 + (l >> 4)*16;
      rbyte ^= (l & 7) << 4;
      const bf16x8 a_pd = *(const bf16x8*)(Pl + rbyte);
      const bf16x8 a_ps = *(const bf16x8*)(Pl + 2048 + rbyte);
#pragma unroll
      for (int df = 0; df < 2; ++df) {
        const bf16x8 bv = *(const bf16x8*)(Vp + (size_t)(df*16 + (l & 15))*1024
                                              + kt*64 + c*32 + (l >> 4)*8);
        acc_dn[df] = __builtin_amdgcn_mfma_f32_16x16x32_bf16(a_pd, bv, acc_dn[df], 0, 0, 0);
        acc_sp[df] = __builtin_amdgcn_mfma_f32_16x16x32_bf16(a_ps, bv, acc_sp[df], 0, 0, 0);
      }
    }
  }

  float a_s = 1.f/(1.f + __expf(-alpha[0]));
  float b_s = 1.f/(1.f + __expf(-beta[0]));
  float wsn = a_s + b_s + 1e-8f;
  float afac = a_s/wsn, bfac = b_s/wsn;
#pragma unroll
  for (int r = 0; r < 4; ++r) {
    int qrow = qt*64 + w*16 + wq + r;
    float is = afac / (ss[r] + 1e-8f);
    float id = bfac / ds[r];
    size_t base = ((size_t)(b*SEQ + qrow))*CDIM + h*32 + (l & 15);
#pragma unroll
    for (int df = 0; df < 2; ++df)
      o_out[base + df*16] = acc_sp[df][r]*is + acc_dn[df][r]*id;
  }
}

// ---------------- small 3x3 conv (SAME) ----------------
__global__ __launch_bounds__(256) void k_conv3(const float* __restrict__ in,
                                               const float* __restrict__ w,
                                               float* __restrict__ out, int Cin) {
  int oc = blockIdx.x;
  int p = blockIdx.y * 256 + threadIdx.x;
  int y = p >> 5, x = p & 31;
  float acc = 0.f;
  for (int c = 0; c < Cin; ++c) {
    const float* ip = in + c*1024;
    const float* wp = w + ((size_t)oc*Cin + c)*9;
#pragma unroll
    for (int i = 0; i < 3; ++i) {
      int yy = y + i - 1;
      if (yy < 0 || yy > 31) continue;
#pragma unroll
      for (int j = 0; j < 3; ++j) {
        int xx = x + j - 1;
        if (xx < 0 || xx > 31) continue;
        acc += ip[yy*32 + xx] * wp[i*3 + j];
      }
    }
  }
  out[oc*1024 + p] = acc;
}

// ---------------- LayerNorm over (C,H,W)=65536 + ReLU ----------------
__global__ __launch_bounds__(1024) void k_lnchw(const float* __restrict__ in,
                                                const float* __restrict__ g,
                                                const float* __restrict__ b,
                                                float* __restrict__ out) {
  __shared__ float red[1024];
  __shared__ float red2[1024];
  int t = threadIdx.x;
  float s = 0.f, sq = 0.f;
  for (int i = t; i < 65536; i += 1024) { float v = in[i]; s += v; sq += v*v; }
  red[t] = s; red2[t] = sq; __syncthreads();
  for (int o = 512; o > 0; o >>= 1) {
    if (t < o) { red[t] += red[t+o]; red2[t] += red2[t+o]; }
    __syncthreads();
  }
  float mean = red[0] * (1.f/65536.f);
  float var  = red2[0] * (1.f/65536.f) - mean*mean;
  float inv = rsqrtf(var + 1e-5f);
  for (int i = t; i < 65536; i += 1024) {
    float v = (in[i] - mean) * inv * g[i] + b[i];
    out[i] = fmaxf(v, 0.f);
  }
}

// ---------------- im2col^T of p (64,32,32) -> pmT[1024 px][576 k] bf16 ----------------
__global__ __launch_bounds__(576) void k_im2colT(const float* __restrict__ pin,
                                                 unsigned short* __restrict__ pmT) {
  int n = blockIdx.x, k = threadIdx.x;
  int c = k / 9, tap = k - c*9;
  int yy = (n >> 5) + tap/3 - 1, xx = (n & 31) + tap%3 - 1;
  float v = (yy >= 0 && yy < 32 && xx >= 0 && xx < 32) ? pin[c*1024 + yy*32 + xx] : 0.f;
  pmT[(size_t)n*576 + k] = (unsigned short)bf16rn(v);
}

__device__ __forceinline__ float gelu_exact(float x) {
  return 0.5f * x * (1.f + erff(x * 0.70710678118654752f));
}

// ------- MFMA cf conv (GEMM 18432x1024x576 bf16) + TVConv + GELU gate -> z -------
__global__ __launch_bounds__(256) void k_cf_tv_mfma(const float* __restrict__ cfw,
                                                    const unsigned short* __restrict__ pmT,
                                                    const float* __restrict__ y,
                                                    float* __restrict__ z) {
  __shared__ __align__(16) char s_lds[47616];
  char* Ab = s_lds;
  const int t = threadIdx.x;
  const int l = t & 63, w = t >> 6;
  const int n0 = blockIdx.x * 64;
  const int c0 = blockIdx.y * 8;

  f32x4 acc[9];
#pragma unroll
  for (int m = 0; m < 9; ++m) acc[m] = (f32x4){0.f, 0.f, 0.f, 0.f};

  float4 sreg[9];

  auto stage_load = [&](int kt) {
    const int k0 = kt * 64;
#pragma unroll
    for (int i = 0; i < 9; ++i) {
      int c = t + i*256;
      int r = c >> 4, s4 = c & 15;
      int grow = (r < 72) ? (c0*9 + r) : (9216 + c0*9 + (r - 72));
      sreg[i] = *(const float4*)(cfw + (size_t)grow*576 + k0 + s4*4);
    }
  };
  auto stage_write = [&](int buf) {
#pragma unroll
    for (int i = 0; i < 9; ++i) {
      int c = t + i*256;
      int r = c >> 4, s4 = c & 15;
      int byte = buf*18432 + r*128 + s4*8;
      byte ^= (r & 7) << 4;
      uint2 u;
      u.x = bf16rn(sreg[i].x) | (bf16rn(sreg[i].y) << 16);
      u.y = bf16rn(sreg[i].z) | (bf16rn(sreg[i].w) << 16);
      *(uint2*)(Ab + byte) = u;
    }
  };

  stage_load(0);
  stage_write(0);
  __syncthreads();

  const unsigned short* pB = pmT + (size_t)(n0 + w*16 + (l & 15))*576 + 8*(l >> 4);
  for (int kt = 0; kt < 9; ++kt) {
    if (kt < 8) stage_load(kt + 1);
    const int coff = (kt & 1) * 18432;
#pragma unroll
    for (int s = 0; s < 2; ++s) {
      const bf16x8 bv = *(const bf16x8*)(pB + kt*64 + s*32);
#pragma unroll
      for (int m = 0; m < 9; ++m) {
        int row = m*16 + (l & 15);
        int byte = coff + row*128 + s*64 + (l >> 4)*16;
        byte ^= (row & 7) << 4;
        bf16x8 av = *(const bf16x8*)(Ab + byte);
        acc[m] = __builtin_amdgcn_mfma_f32_16x16x32_bf16(av, bv, acc[m], 0, 0, 0);
      }
    }
    __syncthreads();
    if (kt < 8) { stage_write((kt + 1) & 1); __syncthreads(); }
  }

  float* W  = (float*)s_lds;             // [144][68]
  float* YL = (float*)(s_lds + 39168);   // [16][4][33]
#pragma unroll
  for (int m = 0; m < 9; ++m)
#pragma unroll
    for (int r = 0; r < 4; ++r)
      W[(m*16 + (l >> 4)*4 + r)*68 + w*16 + (l & 15)] = acc[m][r];
  __syncthreads();

  const int py0 = blockIdx.x * 2;
  const int p = t >> 5, lx = t & 31;
  for (int b = 0; b < 4; ++b) {
    if (b) __syncthreads();
#pragma unroll
    for (int i = 0; i < 8; ++i) {
      int idx = t + i*256;
      int chl = idx >> 7, rem = idx & 127;
      int ry = rem >> 5, px = rem & 31;
      int iy = py0 + ry - 1;
      int chG = (chl < 8) ? (c0 + chl) : (1024 + c0 + chl - 8);
      float v = (iy >= 0 && iy < 32) ? y[((size_t)b*2048 + chG)*1024 + iy*32 + px] : 0.f;
      YL[chl*132 + ry*33 + px] = v;
    }
    __syncthreads();
#pragma unroll
    for (int jj = 0; jj < 2; ++jj) {
      int nL = lx*2 + jj;
      int pyl = nL >> 5, pxl = nL & 31;
      float lo = 0.f, hi = 0.f;
#pragma unroll
      for (int i = 0; i < 9; ++i) {
        int rr = pyl + i/3;
        int ix = pxl + i%3 - 1;
        if (ix < 0 || ix > 31) continue;
        lo += W[(p*9 + i)*68 + nL]      * YL[p*132 + rr*33 + ix];
        hi += W[(72 + p*9 + i)*68 + nL] * YL[(8 + p)*132 + rr*33 + ix];
      }
      z[((size_t)b*1024 + c0 + p)*1024 + n0 + nL] = gelu_exact(lo) * hi;
    }
  }
}

// -------- pout GEMM: OUT[b][m][o] = xr[b][m][o] + sum_c z[b][c][m]*pw[o][c] --------
__global__ __launch_bounds__(256) void k_gemm_pout(const float* __restrict__ zbuf,
                                                   const float* __restrict__ pw,
                                                   const float* __restrict__ xr,
                                                   float* __restrict__ outp) {
  __shared__ float As[16][68];
  __shared__ float Bs[16][68];
  int b = blockIdx.z;
  int m0 = blockIdx.y * 64, n0 = blockIdx.x * 64;
  int t = threadIdx.x;
  const float* zp = zbuf + (size_t)b*1024*1024;
  int ty = t >> 4, tx = t & 15;
  int ak = t >> 4, am = (t & 15) * 4;
  int br = t >> 2, bk = (t & 3) * 4;
  float acc[4][4] = {};
  for (int k0 = 0; k0 < 1024; k0 += 16) {
    float4 av = *(const float4*)&zp[(size_t)(k0 + ak)*1024 + m0 + am];
    float4 bv = *(const float4*)&pw[(size_t)(n0 + br)*1024 + k0 + bk];
    As[ak][am+0]=av.x; As[ak][am+1]=av.y; As[ak][am+2]=av.z; As[ak][am+3]=av.w;
    Bs[bk+0][br]=bv.x; Bs[bk+1][br]=bv.y; Bs[bk+2][br]=bv.z; Bs[bk+3][br]=bv.w;
    __syncthreads();
#pragma unroll
    for (int kk = 0; kk < 16; ++kk) {
      float a[4], bb2[4];
#pragma unroll
      for (int i = 0; i < 4; ++i) a[i] = As[kk][ty*4+i];
#pragma unroll
      for (int j = 0; j < 4; ++j) bb2[j] = Bs[kk][tx*4+j];
#pragma unroll
      for (int i = 0; i < 4; ++i)
#pragma unroll
        for (int j = 0; j < 4; ++j) acc[i][j] += a[i]*bb2[j];
    }
    __syncthreads();
  }
#pragma unroll
  for (int i = 0; i < 4; ++i) {
    int m = m0 + ty*4 + i;
    size_t base = ((size_t)b*1024 + m)*256 + n0 + tx*4;
    float4 rv = *(const float4*)&xr[base];
    float4 ov;
    ov.x = acc[i][0] + rv.x; ov.y = acc[i][1] + rv.y;
    ov.z = acc[i][2] + rv.z; ov.w = acc[i][3] + rv.w;
    *(float4*)&outp[base] = ov;
  }
}

extern "C" void kernel_launch(void* const* d_in, const int* in_sizes, int n_in,
                              void* d_out, int out_size, void* d_ws, size_t ws_size,
                              hipStream_t stream) {
  (void)in_sizes; (void)n_in; (void)out_size; (void)ws_size;
  const float* x      = (const float*)d_in[0];
  const float* n1g    = (const float*)d_in[1];
  const float* n1b    = (const float*)d_in[2];
  const float* qkv_w  = (const float*)d_in[3];
  const float* alpha  = (const float*)d_in[4];
  const float* beta   = (const float*)d_in[5];
  const float* proj_w = (const float*)d_in[6];
  const float* proj_b = (const float*)d_in[7];
  const float* pin_w  = (const float*)d_in[8];
  const float* posi   = (const float*)d_in[9];
  const float* c0w    = (const float*)d_in[10];
  const float* l0g    = (const float*)d_in[11];
  const float* l0b    = (const float*)d_in[12];
  const float* c1w    = (const float*)d_in[13];
  const float* l1g    = (const float*)d_in[14];
  const float* l1b    = (const float*)d_in[15];
  const float* c2w    = (const float*)d_in[16];
  const float* l2g    = (const float*)d_in[17];
  const float* l2b    = (const float*)d_in[18];
  const float* cfw    = (const float*)d_in[19];
  const float* poutw  = (const float*)d_in[20];

  float* ws   = (float*)d_ws;
  unsigned short* h1b = (unsigned short*)(ws + OFF_H1);
  float* qkvb = ws + OFF_QKV;
  float* ob   = ws + OFF_O;
  float* xr   = ws + OFF_XR;
  float* yb   = ws + OFF_Y;
  float* pA   = ws + OFF_PA;
  float* pB   = ws + OFF_PB;
  float* zb   = ws + OFF_Z;
  unsigned short* pmT   = (unsigned short*)(ws + OFF_PMT);
  unsigned short* Qbp   = (unsigned short*)(ws + OFF_QB);
  unsigned short* Kbp   = (unsigned short*)(ws + OFF_KB);
  unsigned short* Vtp   = (unsigned short*)(ws + OFF_VT);
  unsigned short* qkvwb = (unsigned short*)(ws + OFF_QWB);
  unsigned short* pinwb = (unsigned short*)(ws + OFF_PWB);
  unsigned short* xrb   = (unsigned short*)(ws + OFF_XRB);
  float* outp = (float*)d_out;

  // weight conversions (independent of data path)
  k_w2bf<<<768, 256, 0, stream>>>(qkv_w, qkvwb, 768*256);
  k_w2bf<<<2048, 256, 0, stream>>>(pin_w, pinwb, 2048*256);

  // ASSA branch
  k_ln1<<<4096, 256, 0, stream>>>(x, n1g, n1b, h1b);
  k_gemm_bf<<<dim3(12, 64, 1), 256, 0, stream>>>(h1b, qkvwb, qkvb, 768, 0, 0);
  k_qkv2bf<<<4096, 256, 0, stream>>>(qkvb, Qbp, Kbp, Vtp);
  k_attn_mfma<<<512, 256, 0, stream>>>(Qbp, Kbp, Vtp, alpha, beta, ob);
  k_gemm_abt<<<dim3(4, 64, 1), 256, 0, stream>>>(ob, proj_w, xr, proj_b, x,
      256, 256, 256, 256, 0, 0, 0, xrb);
  // FRFN: project_in (per-batch, bf16 MFMA), y[b][o][n]
  k_gemm_bf<<<dim3(16, 32, 4), 256, 0, stream>>>(pinwb, xrb, yb, 1024,
      262144L, 2048L*1024);
  // posi-map conv/LN chain (pA/pB alias dead h1 region)
  k_conv3<<<dim3(64, 4), 256, 0, stream>>>(posi, c0w, pA, 4);
  k_lnchw<<<1, 1024, 0, stream>>>(pA, l0g, l0b, pB);
  k_conv3<<<dim3(64, 4), 256, 0, stream>>>(pB, c1w, pA, 64);
  k_lnchw<<<1, 1024, 0, stream>>>(pA, l1g, l1b, pB);
  k_conv3<<<dim3(64, 4), 256, 0, stream>>>(pB, c2w, pA, 64);
  k_lnchw<<<1, 1024, 0, stream>>>(pA, l2g, l2b, pB);
  k_im2colT<<<1024, 576, 0, stream>>>(pB, pmT);
  // MFMA cf conv GEMM + TVConv + gate -> z (aliases dead h1+qkv region)
  k_cf_tv_mfma<<<dim3(16, 128, 1), 256, 0, stream>>>(cfw, pmT, yb, zb);
  // project_out + residual -> d_out
  k_gemm_pout<<<dim3(4, 16, 4), 256, 0, stream>>>(zb, poutw, xr, outp);
}